// Round 1
// baseline (2064.369 us; speedup 1.0000x reference)
//
#include <hip/hip_runtime.h>

// Constellation CNN, fp32 reference-faithful implementation.
// Pipeline: scatter+conv1+pool -> conv2+pool -> conv3+pool+pool -> fc1+prelu+fc2
// ws layout: [out3: 1024*128*16 f32 = 8MB][out1: C*32*32*32 f32][out2: C*64*16*16 f32]

__device__ __forceinline__ float prelu(float v, float a) {
    return v > 0.0f ? v : a * v;
}

// ---------------- Kernel 1: scatter -> conv1(3x3,pad1)+b+prelu -> avgpool2 ----------------
// grid: C blocks (one per image), 256 threads. out1: [C,32,32,32]
__global__ __launch_bounds__(256) void k_scat_conv1(
    const float* __restrict__ x, const float* __restrict__ w1,
    const float* __restrict__ b1, const float* __restrict__ a1,
    float* __restrict__ out1, int b0)
{
    __shared__ float img[66 * 66];   // padded (+1 halo) constellation
    __shared__ float ws[32 * 9];
    __shared__ float bs[32];
    const int t = threadIdx.x;
    const int bl = blockIdx.x;
    const int b = b0 + bl;

    for (int i = t; i < 66 * 66; i += 256) img[i] = 0.0f;
    for (int i = t; i < 288; i += 256) ws[i] = w1[i];
    if (t < 32) bs[t] = b1[t];
    __syncthreads();

    const float* xb = x + (size_t)b * 8192;
    for (int s = t; s < 4096; s += 256) {
        float xi = xb[s];
        float xq = xb[4096 + s];
        int ii = (int)(xi * 16.0f + 32.0f);   // trunc toward zero == astype(int32)
        int qi = (int)(xq * 16.0f + 32.0f);
        ii = min(max(ii, 0), 63);
        qi = min(max(qi, 0), 63);
        img[(qi + 1) * 66 + (ii + 1)] = 1.0f; // duplicates collapse, benign race
    }
    __syncthreads();

    const float alpha = a1[0];
    float* ob = out1 + (size_t)bl * 32 * 1024;
    for (int i = 0; i < 4; ++i) {
        int p = i * 256 + t;            // pooled position 0..1023
        int py = p >> 5, px = p & 31;
        float v[4][4];
        #pragma unroll
        for (int r = 0; r < 4; ++r)
            #pragma unroll
            for (int c = 0; c < 4; ++c)
                v[r][c] = img[(2 * py + r) * 66 + (2 * px + c)];
        for (int c = 0; c < 32; ++c) {
            float w[9];
            #pragma unroll
            for (int k = 0; k < 9; ++k) w[k] = ws[c * 9 + k];
            float s00 = 0.f, s01 = 0.f, s10 = 0.f, s11 = 0.f;
            #pragma unroll
            for (int ky = 0; ky < 3; ++ky)
                #pragma unroll
                for (int kx = 0; kx < 3; ++kx) {
                    float wk = w[ky * 3 + kx];
                    s00 = fmaf(v[ky][kx],         wk, s00);
                    s01 = fmaf(v[ky][kx + 1],     wk, s01);
                    s10 = fmaf(v[ky + 1][kx],     wk, s10);
                    s11 = fmaf(v[ky + 1][kx + 1], wk, s11);
                }
            float bb = bs[c];
            float o = 0.25f * (prelu(s00 + bb, alpha) + prelu(s01 + bb, alpha) +
                               prelu(s10 + bb, alpha) + prelu(s11 + bb, alpha));
            ob[c * 1024 + p] = o;
        }
    }
}

// ---------------- Kernel 2: conv2(3x3,pad1,32->64)+b+prelu -> avgpool2 ----------------
// grid: 4*C blocks (image x quadrant), 256 threads = 64 co x 4 spatial groups.
// in1: [C,32,32,32]  out2: [C,64,16,16]
__global__ __launch_bounds__(256) void k_conv2(
    const float* __restrict__ in1, const float* __restrict__ w2,
    const float* __restrict__ b2, const float* __restrict__ a2,
    float* __restrict__ out2)
{
    __shared__ float tin[32 * 18 * 18]; // 41.5 KB: 32ci x (16+2halo)^2
    const int t = threadIdx.x;
    const int bl = blockIdx.x >> 2;
    const int q = blockIdx.x & 3;
    const int qy = (q >> 1) * 16, qx = (q & 1) * 16; // pre-pool tile origin in 32x32

    for (int idx = t; idx < 32 * 324; idx += 256) {
        int ci = idx / 324;
        int r = idx - ci * 324;
        int y = r / 18;
        int xx = r - y * 18;
        int gy = qy + y - 1, gx = qx + xx - 1;
        float v = 0.0f;
        if (gy >= 0 && gy < 32 && gx >= 0 && gx < 32)
            v = in1[(size_t)(bl * 32 + ci) * 1024 + gy * 32 + gx];
        tin[idx] = v;
    }
    __syncthreads();

    const int co = t & 63;
    const int g = t >> 6;                    // uniform per wave
    const int y0 = (g >> 1) * 8, x0 = (g & 1) * 8; // 8x8 pre-pool sub-tile (tile-local)

    float acc[8][8];
    #pragma unroll
    for (int i = 0; i < 8; ++i)
        #pragma unroll
        for (int j = 0; j < 8; ++j) acc[i][j] = 0.0f;

    for (int ci = 0; ci < 32; ++ci) {
        const float* wp = w2 + ((size_t)co * 32 + ci) * 9;
        float w[9];
        #pragma unroll
        for (int k = 0; k < 9; ++k) w[k] = wp[k];
        const float* ip = tin + ci * 324;
        #pragma unroll
        for (int dy = 0; dy < 10; ++dy) {
            int iy = y0 + dy;                // halo-tile row; conv(y,x)=sum tin[y+ky][x+kx]
            float row[10];
            #pragma unroll
            for (int j = 0; j < 10; ++j) row[j] = ip[iy * 18 + x0 + j];
            #pragma unroll
            for (int ky = 0; ky < 3; ++ky) {
                const int oy = dy - ky;      // static
                if (oy >= 0 && oy < 8) {
                    #pragma unroll
                    for (int ox = 0; ox < 8; ++ox)
                        #pragma unroll
                        for (int kx = 0; kx < 3; ++kx)
                            acc[oy][ox] = fmaf(row[ox + kx], w[ky * 3 + kx], acc[oy][ox]);
                }
            }
        }
    }

    const float alpha = a2[0];
    const float bb = b2[co];
    float* ob = out2 + (size_t)(bl * 64 + co) * 256;
    #pragma unroll
    for (int py = 0; py < 4; ++py)
        #pragma unroll
        for (int px = 0; px < 4; ++px) {
            float o = 0.25f * (prelu(acc[2*py][2*px] + bb, alpha) +
                               prelu(acc[2*py][2*px+1] + bb, alpha) +
                               prelu(acc[2*py+1][2*px] + bb, alpha) +
                               prelu(acc[2*py+1][2*px+1] + bb, alpha));
            int gpy = (qy >> 1) + (y0 >> 1) + py;
            int gpx = (qx >> 1) + (x0 >> 1) + px;
            ob[gpy * 16 + gpx] = o;
        }
}

// ---------------- Kernel 3: conv3(5x5,pad2,64->128)+b+prelu -> pool -> pool ----------------
// grid: C blocks (one per image), 512 threads = 128 co x 4 spatial groups.
// in2: [C,64,16,16]  out3: [1024,128,4,4] (global batch index)
__global__ __launch_bounds__(512) void k_conv3(
    const float* __restrict__ in2, const float* __restrict__ w3,
    const float* __restrict__ b3, const float* __restrict__ a3,
    float* __restrict__ out3, int b0)
{
    __shared__ float tin[4 * 256];      // 4 ci x 16x16
    __shared__ float tw[4 * 128 * 25];  // 51.2 KB, layout [ci][co][25]
    const int t = threadIdx.x;
    const int bl = blockIdx.x;
    const int co = t & 127;
    const int g = t >> 7;                       // uniform per wave
    const int y0 = (g >> 1) * 8, x0 = (g & 1) * 8;

    float acc[8][8];
    #pragma unroll
    for (int i = 0; i < 8; ++i)
        #pragma unroll
        for (int j = 0; j < 8; ++j) acc[i][j] = 0.0f;

    for (int cc = 0; cc < 16; ++cc) {           // 16 chunks of 4 input channels
        __syncthreads();
        for (int idx = t; idx < 1024; idx += 512) {
            int ci = idx >> 8;
            tin[idx] = in2[(size_t)(bl * 64 + cc * 4 + ci) * 256 + (idx & 255)];
        }
        for (int idx = t; idx < 12800; idx += 512) {
            int ci = idx / 3200;
            int r = idx - ci * 3200;
            int c2 = r / 25;
            int k = r - c2 * 25;
            tw[idx] = w3[((size_t)c2 * 64 + (cc * 4 + ci)) * 25 + k];
        }
        __syncthreads();

        for (int ci = 0; ci < 4; ++ci) {
            float w[25];
            const float* wp = tw + ci * 3200 + co * 25;
            #pragma unroll
            for (int k = 0; k < 25; ++k) w[k] = wp[k];
            const float* ip = tin + ci * 256;
            #pragma unroll
            for (int dy = 0; dy < 12; ++dy) {
                int iy = y0 + dy - 2;
                if (iy >= 0 && iy < 16) {
                    float row[12];
                    #pragma unroll
                    for (int j = 0; j < 12; ++j) {
                        int xx = x0 + j - 2;
                        row[j] = (xx >= 0 && xx < 16) ? ip[iy * 16 + xx] : 0.0f;
                    }
                    #pragma unroll
                    for (int ky = 0; ky < 5; ++ky) {
                        const int oy = dy - ky;   // static: out y = iy+2-ky
                        if (oy >= 0 && oy < 8) {
                            #pragma unroll
                            for (int ox = 0; ox < 8; ++ox)
                                #pragma unroll
                                for (int kx = 0; kx < 5; ++kx)
                                    acc[oy][ox] = fmaf(row[ox + kx], w[ky * 5 + kx], acc[oy][ox]);
                        }
                    }
                }
            }
        }
    }

    const float alpha = a3[0];
    const float bb = b3[co];
    const int b = b0 + bl;
    float* ob = out3 + (size_t)(b * 128 + co) * 16;
    #pragma unroll
    for (int u = 0; u < 2; ++u)
        #pragma unroll
        for (int v = 0; v < 2; ++v) {
            float s = 0.0f;
            #pragma unroll
            for (int i = 0; i < 4; ++i)
                #pragma unroll
                for (int j = 0; j < 4; ++j)
                    s += prelu(acc[4 * u + i][4 * v + j] + bb, alpha);
            int fy = (y0 >> 2) + u, fx = (x0 >> 2) + v;
            ob[fy * 4 + fx] = s * (1.0f / 16.0f);
        }
}

// ---------------- Kernel 4: fc1(2048->256)+b+prelu, fc2(256->128)+b ----------------
// grid: 256 blocks x 4 batch rows, 256 threads. h: [1024,2048] (== out3 flat), out: [1024,128]
__global__ __launch_bounds__(256) void k_fc(
    const float* __restrict__ h, const float* __restrict__ wc1,
    const float* __restrict__ bc1, const float* __restrict__ ac,
    const float* __restrict__ wc2, const float* __restrict__ bc2,
    float* __restrict__ out)
{
    __shared__ float xr[4][2048];  // 32 KB
    __shared__ float hid[4][256];  // 4 KB
    const int t = threadIdx.x;
    const int r0 = blockIdx.x * 4;

    for (int idx = t; idx < 4 * 2048; idx += 256) {
        int r = idx >> 11;
        int k = idx & 2047;
        xr[r][k] = h[(size_t)(r0 + r) * 2048 + k];
    }
    __syncthreads();

    {
        float acc[4] = {0.f, 0.f, 0.f, 0.f};
        const float* wp = wc1 + (size_t)t * 2048;
        for (int k = 0; k < 2048; k += 4) {
            float4 w4 = *(const float4*)(wp + k);
            #pragma unroll
            for (int r = 0; r < 4; ++r) {
                acc[r] = fmaf(xr[r][k + 0], w4.x, acc[r]);
                acc[r] = fmaf(xr[r][k + 1], w4.y, acc[r]);
                acc[r] = fmaf(xr[r][k + 2], w4.z, acc[r]);
                acc[r] = fmaf(xr[r][k + 3], w4.w, acc[r]);
            }
        }
        float bb = bc1[t];
        float alpha = ac[0];
        #pragma unroll
        for (int r = 0; r < 4; ++r) hid[r][t] = prelu(acc[r] + bb, alpha);
    }
    __syncthreads();

    {
        const int o = t & 127;
        const int rb = (t >> 7) * 2;
        float acc[2] = {0.f, 0.f};
        const float* wp = wc2 + (size_t)o * 256;
        for (int k = 0; k < 256; k += 4) {
            float4 w4 = *(const float4*)(wp + k);
            #pragma unroll
            for (int rr = 0; rr < 2; ++rr) {
                acc[rr] = fmaf(hid[rb + rr][k + 0], w4.x, acc[rr]);
                acc[rr] = fmaf(hid[rb + rr][k + 1], w4.y, acc[rr]);
                acc[rr] = fmaf(hid[rb + rr][k + 2], w4.z, acc[rr]);
                acc[rr] = fmaf(hid[rb + rr][k + 3], w4.w, acc[rr]);
            }
        }
        float bb = bc2[o];
        out[(size_t)(r0 + rb) * 128 + o] = acc[0] + bb;
        out[(size_t)(r0 + rb + 1) * 128 + o] = acc[1] + bb;
    }
}

extern "C" void kernel_launch(void* const* d_in, const int* in_sizes, int n_in,
                              void* d_out, int out_size, void* d_ws, size_t ws_size,
                              hipStream_t stream) {
    const float* x   = (const float*)d_in[0];
    const float* w1  = (const float*)d_in[1];
    const float* b1  = (const float*)d_in[2];
    const float* a1  = (const float*)d_in[3];
    const float* w2  = (const float*)d_in[4];
    const float* b2  = (const float*)d_in[5];
    const float* a2  = (const float*)d_in[6];
    const float* w3  = (const float*)d_in[7];
    const float* b3  = (const float*)d_in[8];
    const float* a3  = (const float*)d_in[9];
    const float* wc1 = (const float*)d_in[10];
    const float* bc1 = (const float*)d_in[11];
    const float* ac  = (const float*)d_in[12];
    const float* wc2 = (const float*)d_in[13];
    const float* bc2 = (const float*)d_in[14];
    float* out = (float*)d_out;

    const size_t OUT3_BYTES = (size_t)1024 * 128 * 16 * 4; // 8 MB
    // per-image scratch: out1 = 128KB, out2 = 64KB
    int C = 256;
    while (C > 1 && OUT3_BYTES + (size_t)C * (131072 + 65536) > ws_size) C >>= 1;

    float* out3 = (float*)d_ws;
    float* out1 = (float*)((char*)d_ws + OUT3_BYTES);
    float* out2 = out1 + (size_t)C * 32 * 1024;

    const int nchunk = 1024 / C;
    for (int c = 0; c < nchunk; ++c) {
        int b0 = c * C;
        k_scat_conv1<<<C, 256, 0, stream>>>(x, w1, b1, a1, out1, b0);
        k_conv2<<<4 * C, 256, 0, stream>>>(out1, w2, b2, a2, out2);
        k_conv3<<<C, 512, 0, stream>>>(out2, w3, b3, a3, out3, b0);
    }
    k_fc<<<256, 256, 0, stream>>>(out3, wc1, bc1, ac, wc2, bc2, out);
}

// Round 2
// 768.102 us; speedup vs baseline: 2.6876x; 2.6876x over previous
//
#include <hip/hip_runtime.h>

// Constellation CNN. conv3 -> bf16 MFMA implicit GEMM (weights hi/lo split, 2-term).
// ws layout: [out3 8MB][whi 400KB][wlo 400KB][out1 C*128KB][out2 C*64KB]

typedef short s16x8 __attribute__((ext_vector_type(8)));
typedef float f32x4 __attribute__((ext_vector_type(4)));

__device__ __forceinline__ float prelu(float v, float a) {
    return v > 0.0f ? v : a * v;
}
__device__ __forceinline__ unsigned short bf16_rn(float x) {
    union { float f; unsigned u; } a; a.f = x;
    unsigned r = a.u + 0x7FFF + ((a.u >> 16) & 1);
    return (unsigned short)(r >> 16);
}
__device__ __forceinline__ float bf16_tof(unsigned short h) {
    union { unsigned u; float f; } a; a.u = (unsigned)h << 16;
    return a.f;
}

// ---------------- Kernel 0: prepack conv3 weights into MFMA fragment order ----------------
// w3 [128co][64ci][25tap] f32 -> whi/wlo [tap][kk2][g4][co128][i8] bf16 (ci = kk*32+g*8+i)
__global__ __launch_bounds__(256) void k_prepack(
    const float* __restrict__ w3, unsigned short* __restrict__ whi,
    unsigned short* __restrict__ wlo)
{
    int e = blockIdx.x * 256 + threadIdx.x;      // 0 .. 204799
    int i  = e & 7;
    int co = (e >> 3) & 127;
    int g  = (e >> 10) & 3;
    int kk = (e >> 12) & 1;
    int tp = e >> 13;
    int ci = kk * 32 + g * 8 + i;
    float w = w3[((size_t)co * 64 + ci) * 25 + tp];
    unsigned short h = bf16_rn(w);
    float r = w - bf16_tof(h);
    whi[e] = h;
    wlo[e] = bf16_rn(r);
}

// ---------------- Kernel 1: scatter -> conv1(3x3,pad1)+b+prelu -> avgpool2 ----------------
__global__ __launch_bounds__(256) void k_scat_conv1(
    const float* __restrict__ x, const float* __restrict__ w1,
    const float* __restrict__ b1, const float* __restrict__ a1,
    float* __restrict__ out1, int b0)
{
    __shared__ float img[66 * 66];
    __shared__ float ws[32 * 9];
    __shared__ float bs[32];
    const int t = threadIdx.x;
    const int bl = blockIdx.x;
    const int b = b0 + bl;

    for (int i = t; i < 66 * 66; i += 256) img[i] = 0.0f;
    for (int i = t; i < 288; i += 256) ws[i] = w1[i];
    if (t < 32) bs[t] = b1[t];
    __syncthreads();

    const float* xb = x + (size_t)b * 8192;
    for (int s = t; s < 4096; s += 256) {
        float xi = xb[s];
        float xq = xb[4096 + s];
        int ii = (int)(xi * 16.0f + 32.0f);
        int qi = (int)(xq * 16.0f + 32.0f);
        ii = min(max(ii, 0), 63);
        qi = min(max(qi, 0), 63);
        img[(qi + 1) * 66 + (ii + 1)] = 1.0f;
    }
    __syncthreads();

    const float alpha = a1[0];
    float* ob = out1 + (size_t)bl * 32 * 1024;
    for (int i = 0; i < 4; ++i) {
        int p = i * 256 + t;
        int py = p >> 5, px = p & 31;
        float v[4][4];
        #pragma unroll
        for (int r = 0; r < 4; ++r)
            #pragma unroll
            for (int c = 0; c < 4; ++c)
                v[r][c] = img[(2 * py + r) * 66 + (2 * px + c)];
        for (int c = 0; c < 32; ++c) {
            float w[9];
            #pragma unroll
            for (int k = 0; k < 9; ++k) w[k] = ws[c * 9 + k];
            float s00 = 0.f, s01 = 0.f, s10 = 0.f, s11 = 0.f;
            #pragma unroll
            for (int ky = 0; ky < 3; ++ky)
                #pragma unroll
                for (int kx = 0; kx < 3; ++kx) {
                    float wk = w[ky * 3 + kx];
                    s00 = fmaf(v[ky][kx],         wk, s00);
                    s01 = fmaf(v[ky][kx + 1],     wk, s01);
                    s10 = fmaf(v[ky + 1][kx],     wk, s10);
                    s11 = fmaf(v[ky + 1][kx + 1], wk, s11);
                }
            float bb = bs[c];
            float o = 0.25f * (prelu(s00 + bb, alpha) + prelu(s01 + bb, alpha) +
                               prelu(s10 + bb, alpha) + prelu(s11 + bb, alpha));
            ob[c * 1024 + p] = o;
        }
    }
}

// ---------------- Kernel 2: conv2(3x3,pad1,32->64)+b+prelu -> avgpool2 ----------------
__global__ __launch_bounds__(256) void k_conv2(
    const float* __restrict__ in1, const float* __restrict__ w2,
    const float* __restrict__ b2, const float* __restrict__ a2,
    float* __restrict__ out2)
{
    __shared__ float tin[32 * 18 * 18];
    const int t = threadIdx.x;
    const int bl = blockIdx.x >> 2;
    const int q = blockIdx.x & 3;
    const int qy = (q >> 1) * 16, qx = (q & 1) * 16;

    for (int idx = t; idx < 32 * 324; idx += 256) {
        int ci = idx / 324;
        int r = idx - ci * 324;
        int y = r / 18;
        int xx = r - y * 18;
        int gy = qy + y - 1, gx = qx + xx - 1;
        float v = 0.0f;
        if (gy >= 0 && gy < 32 && gx >= 0 && gx < 32)
            v = in1[(size_t)(bl * 32 + ci) * 1024 + gy * 32 + gx];
        tin[idx] = v;
    }
    __syncthreads();

    const int co = t & 63;
    const int g = t >> 6;
    const int y0 = (g >> 1) * 8, x0 = (g & 1) * 8;

    float acc[8][8];
    #pragma unroll
    for (int i = 0; i < 8; ++i)
        #pragma unroll
        for (int j = 0; j < 8; ++j) acc[i][j] = 0.0f;

    for (int ci = 0; ci < 32; ++ci) {
        const float* wp = w2 + ((size_t)co * 32 + ci) * 9;
        float w[9];
        #pragma unroll
        for (int k = 0; k < 9; ++k) w[k] = wp[k];
        const float* ip = tin + ci * 324;
        #pragma unroll
        for (int dy = 0; dy < 10; ++dy) {
            int iy = y0 + dy;
            float row[10];
            #pragma unroll
            for (int j = 0; j < 10; ++j) row[j] = ip[iy * 18 + x0 + j];
            #pragma unroll
            for (int ky = 0; ky < 3; ++ky) {
                const int oy = dy - ky;
                if (oy >= 0 && oy < 8) {
                    #pragma unroll
                    for (int ox = 0; ox < 8; ++ox)
                        #pragma unroll
                        for (int kx = 0; kx < 3; ++kx)
                            acc[oy][ox] = fmaf(row[ox + kx], w[ky * 3 + kx], acc[oy][ox]);
                }
            }
        }
    }

    const float alpha = a2[0];
    const float bb = b2[co];
    float* ob = out2 + (size_t)(bl * 64 + co) * 256;
    #pragma unroll
    for (int py = 0; py < 4; ++py)
        #pragma unroll
        for (int px = 0; px < 4; ++px) {
            float o = 0.25f * (prelu(acc[2*py][2*px] + bb, alpha) +
                               prelu(acc[2*py][2*px+1] + bb, alpha) +
                               prelu(acc[2*py+1][2*px] + bb, alpha) +
                               prelu(acc[2*py+1][2*px+1] + bb, alpha));
            int gpy = (qy >> 1) + (y0 >> 1) + py;
            int gpx = (qx >> 1) + (x0 >> 1) + px;
            ob[gpy * 16 + gpx] = o;
        }
}

// ---------------- Kernel 3: conv3 via bf16 MFMA implicit GEMM ----------------
// block = (image, y-half). 8 waves = 4 m-pairs x 2 n-halves.
// Per tap: D[co][p] += W_hi/lo[co][ci] x In_bf16[ci][p_shifted].
// A frag: row co = mtile*16+(l&15), k: ci = kk*32+(l>>4)*8+i  (prepacked, global/L2)
// B frag: col p  = row y, x=(l&15); k same ci mapping (LDS, padded halo)
// C/D:    col = l&15 (x), row = (l>>4)*4+r (co within tile)
__global__ __launch_bounds__(512) void k_conv3_mfma(
    const float* __restrict__ in2, const unsigned short* __restrict__ whi,
    const unsigned short* __restrict__ wlo, const float* __restrict__ b3,
    const float* __restrict__ a3, float* __restrict__ out3, int b0)
{
    __shared__ __align__(16) unsigned short lb[4 * 12 * 20 * 8]; // [cg][ly][x][i8] bf16
    __shared__ float bs[128];

    const int t = threadIdx.x;
    const int bl = blockIdx.x >> 1;
    const int yb = blockIdx.x & 1;
    const int lane = t & 63;
    const int w = t >> 6;
    const int mp = w >> 1;        // 0..3 -> m-tiles {2mp, 2mp+1}
    const int nh = w & 1;         // 0..1 -> rows {4nh..4nh+3} (local to half)
    const int lg = lane >> 4;     // 0..3
    const int lo16 = lane & 15;

    if (t < 128) bs[t] = b3[t];

    const f32x4 zf = {0.f, 0.f, 0.f, 0.f};
    f32x4 acc[2][4];
    #pragma unroll
    for (int m = 0; m < 2; ++m)
        #pragma unroll
        for (int n = 0; n < 4; ++n) acc[m][n] = zf;

    const s16x8 zz = {0, 0, 0, 0, 0, 0, 0, 0};

    for (int kk = 0; kk < 2; ++kk) {
        __syncthreads();
        // zero-fill (halo)
        for (int idx = t; idx < 960; idx += 512)
            reinterpret_cast<s16x8*>(lb)[idx] = zz;
        __syncthreads();
        // stage 32 ci x 12 rows x 16 cols (rows yb*8-2 .. yb*8+9), RN bf16
        for (int idx = t; idx < 6144; idx += 512) {
            int x = idx & 15, rest = idx >> 4, ci = rest & 31, ly = rest >> 5;
            int row = yb * 8 + ly - 2;
            if (row >= 0 && row < 16) {
                float v = in2[((size_t)bl * 64 + kk * 32 + ci) * 256 + row * 16 + x];
                lb[(((ci >> 3) * 12 + ly) * 20 + (x + 2)) * 8 + (ci & 7)] = bf16_rn(v);
            }
        }
        __syncthreads();

        for (int tap = 0; tap < 25; ++tap) {
            int dy = tap / 5, dx = tap - dy * 5;
            const size_t wbase = ((size_t)(tap * 2 + kk) * 4 + lg) * 1024
                               + (size_t)(mp * 32 + lo16) * 8;
            s16x8 ah0 = *reinterpret_cast<const s16x8*>(whi + wbase);
            s16x8 al0 = *reinterpret_cast<const s16x8*>(wlo + wbase);
            s16x8 ah1 = *reinterpret_cast<const s16x8*>(whi + wbase + 128);
            s16x8 al1 = *reinterpret_cast<const s16x8*>(wlo + wbase + 128);
            #pragma unroll
            for (int n = 0; n < 4; ++n) {
                int ly = nh * 4 + n + dy;              // 0..11
                int ax = lo16 + dx;                    // 0..19
                s16x8 bfrag = *reinterpret_cast<const s16x8*>(
                    &lb[((lg * 12 + ly) * 20 + ax) * 8]);
                acc[0][n] = __builtin_amdgcn_mfma_f32_16x16x32_bf16(ah0, bfrag, acc[0][n], 0, 0, 0);
                acc[0][n] = __builtin_amdgcn_mfma_f32_16x16x32_bf16(al0, bfrag, acc[0][n], 0, 0, 0);
                acc[1][n] = __builtin_amdgcn_mfma_f32_16x16x32_bf16(ah1, bfrag, acc[1][n], 0, 0, 0);
                acc[1][n] = __builtin_amdgcn_mfma_f32_16x16x32_bf16(al1, bfrag, acc[1][n], 0, 0, 0);
            }
        }
    }

    // epilogue: bias + prelu + 4x4 mean (two stacked 2x2 pools) -> out3[b][co][fy][fx]
    const float alpha = a3[0];
    const int b = b0 + bl;
    const int fy = yb * 2 + nh;
    const int fx = lo16 >> 2;
    #pragma unroll
    for (int m = 0; m < 2; ++m) {
        const int cobase = mp * 32 + m * 16 + lg * 4;
        #pragma unroll
        for (int r = 0; r < 4; ++r) {
            float bb = bs[cobase + r];
            float s = 0.f;
            #pragma unroll
            for (int n = 0; n < 4; ++n) {
                float v = acc[m][n][r] + bb;
                s += v > 0.f ? v : alpha * v;
            }
            s += __shfl_xor(s, 1, 64);
            s += __shfl_xor(s, 2, 64);
            if ((lane & 3) == 0)
                out3[((size_t)b * 128 + cobase + r) * 16 + fy * 4 + fx] = s * 0.0625f;
        }
    }
}

// ---------------- Kernel 4: fc1(2048->256)+b+prelu, fc2(256->128)+b ----------------
__global__ __launch_bounds__(256) void k_fc(
    const float* __restrict__ h, const float* __restrict__ wc1,
    const float* __restrict__ bc1, const float* __restrict__ ac,
    const float* __restrict__ wc2, const float* __restrict__ bc2,
    float* __restrict__ out)
{
    __shared__ float xr[4][2048];
    __shared__ float hid[4][256];
    const int t = threadIdx.x;
    const int r0 = blockIdx.x * 4;

    for (int idx = t; idx < 4 * 2048; idx += 256) {
        int r = idx >> 11;
        int k = idx & 2047;
        xr[r][k] = h[(size_t)(r0 + r) * 2048 + k];
    }
    __syncthreads();

    {
        float acc[4] = {0.f, 0.f, 0.f, 0.f};
        const float* wp = wc1 + (size_t)t * 2048;
        for (int k = 0; k < 2048; k += 4) {
            float4 w4 = *(const float4*)(wp + k);
            #pragma unroll
            for (int r = 0; r < 4; ++r) {
                acc[r] = fmaf(xr[r][k + 0], w4.x, acc[r]);
                acc[r] = fmaf(xr[r][k + 1], w4.y, acc[r]);
                acc[r] = fmaf(xr[r][k + 2], w4.z, acc[r]);
                acc[r] = fmaf(xr[r][k + 3], w4.w, acc[r]);
            }
        }
        float bb = bc1[t];
        float alpha = ac[0];
        #pragma unroll
        for (int r = 0; r < 4; ++r) hid[r][t] = prelu(acc[r] + bb, alpha);
    }
    __syncthreads();

    {
        const int o = t & 127;
        const int rb = (t >> 7) * 2;
        float acc[2] = {0.f, 0.f};
        const float* wp = wc2 + (size_t)o * 256;
        for (int k = 0; k < 256; k += 4) {
            float4 w4 = *(const float4*)(wp + k);
            #pragma unroll
            for (int rr = 0; rr < 2; ++rr) {
                acc[rr] = fmaf(hid[rb + rr][k + 0], w4.x, acc[rr]);
                acc[rr] = fmaf(hid[rb + rr][k + 1], w4.y, acc[rr]);
                acc[rr] = fmaf(hid[rb + rr][k + 2], w4.z, acc[rr]);
                acc[rr] = fmaf(hid[rb + rr][k + 3], w4.w, acc[rr]);
            }
        }
        float bb = bc2[o];
        out[(size_t)(r0 + rb) * 128 + o] = acc[0] + bb;
        out[(size_t)(r0 + rb + 1) * 128 + o] = acc[1] + bb;
    }
}

extern "C" void kernel_launch(void* const* d_in, const int* in_sizes, int n_in,
                              void* d_out, int out_size, void* d_ws, size_t ws_size,
                              hipStream_t stream) {
    const float* x   = (const float*)d_in[0];
    const float* w1  = (const float*)d_in[1];
    const float* b1  = (const float*)d_in[2];
    const float* a1  = (const float*)d_in[3];
    const float* w2  = (const float*)d_in[4];
    const float* b2  = (const float*)d_in[5];
    const float* a2  = (const float*)d_in[6];
    const float* w3  = (const float*)d_in[7];
    const float* b3  = (const float*)d_in[8];
    const float* a3  = (const float*)d_in[9];
    const float* wc1 = (const float*)d_in[10];
    const float* bc1 = (const float*)d_in[11];
    const float* ac  = (const float*)d_in[12];
    const float* wc2 = (const float*)d_in[13];
    const float* bc2 = (const float*)d_in[14];
    float* out = (float*)d_out;

    const size_t OUT3_BYTES = (size_t)1024 * 128 * 16 * 4;  // 8 MB
    const size_t WPK_BYTES  = (size_t)204800 * 2 * 2;       // 800 KB (hi+lo)
    int C = 1024;
    while (C > 1 && OUT3_BYTES + WPK_BYTES + (size_t)C * (131072 + 65536) > ws_size) C >>= 1;

    float* out3 = (float*)d_ws;
    unsigned short* whi = (unsigned short*)((char*)d_ws + OUT3_BYTES);
    unsigned short* wlo = whi + 204800;
    float* out1 = (float*)((char*)d_ws + OUT3_BYTES + WPK_BYTES);
    float* out2 = out1 + (size_t)C * 32768;

    k_prepack<<<800, 256, 0, stream>>>(w3, whi, wlo);

    const int nchunk = 1024 / C;
    for (int c = 0; c < nchunk; ++c) {
        int b0 = c * C;
        k_scat_conv1<<<C, 256, 0, stream>>>(x, w1, b1, a1, out1, b0);
        k_conv2<<<4 * C, 256, 0, stream>>>(out1, w2, b2, a2, out2);
        k_conv3_mfma<<<2 * C, 512, 0, stream>>>(out2, whi, wlo, b3, a3, out3, b0);
    }
    k_fc<<<256, 256, 0, stream>>>(out3, wc1, bc1, ac, wc2, bc2, out);
}

// Round 3
// 468.972 us; speedup vs baseline: 4.4019x; 1.6378x over previous
//
#include <hip/hip_runtime.h>

// Constellation CNN. conv2+conv3 -> bf16 MFMA implicit GEMM (weights hi/lo split).
// Intermediates out1/out2 stored as bf16. out3 f32.
// ws: [out3 8MB][whi3 400K][wlo3 400K][whi2 36K][wlo2 36K][out1 C*64K][out2 C*32K]

typedef short s16x8 __attribute__((ext_vector_type(8)));
typedef float f32x4 __attribute__((ext_vector_type(4)));

__device__ __forceinline__ float prelu(float v, float a) {
    return v > 0.0f ? v : a * v;
}
__device__ __forceinline__ unsigned short bf16_rn(float x) {
    union { float f; unsigned u; } a; a.f = x;
    unsigned r = a.u + 0x7FFF + ((a.u >> 16) & 1);
    return (unsigned short)(r >> 16);
}
__device__ __forceinline__ float bf16_tof(unsigned short h) {
    union { unsigned u; float f; } a; a.u = (unsigned)h << 16;
    return a.f;
}

// ---------------- Prepack conv3 weights: w3[128co][64ci][25t] -> [t][kk2][g4][co128][i8] ----
__global__ __launch_bounds__(256) void k_prepack3(
    const float* __restrict__ w3, unsigned short* __restrict__ whi,
    unsigned short* __restrict__ wlo)
{
    int e = blockIdx.x * 256 + threadIdx.x;      // 0 .. 204799
    int i  = e & 7;
    int co = (e >> 3) & 127;
    int g  = (e >> 10) & 3;
    int kk = (e >> 12) & 1;
    int tp = e >> 13;
    int ci = kk * 32 + g * 8 + i;
    float w = w3[((size_t)co * 64 + ci) * 25 + tp];
    unsigned short h = bf16_rn(w);
    whi[e] = h;
    wlo[e] = bf16_rn(w - bf16_tof(h));
}

// ---------------- Prepack conv2 weights: w2[64co][32ci][9t] -> [t][g4][co64][i8] ----
__global__ __launch_bounds__(256) void k_prepack2(
    const float* __restrict__ w2, unsigned short* __restrict__ whi,
    unsigned short* __restrict__ wlo)
{
    int e = blockIdx.x * 256 + threadIdx.x;      // 0 .. 18431
    int i  = e & 7;
    int co = (e >> 3) & 63;
    int g  = (e >> 9) & 3;
    int tp = e >> 11;
    int ci = g * 8 + i;
    float w = w2[((size_t)co * 32 + ci) * 9 + tp];
    unsigned short h = bf16_rn(w);
    whi[e] = h;
    wlo[e] = bf16_rn(w - bf16_tof(h));
}

// ---------------- Kernel 1: scatter -> conv1(3x3,pad1)+b+prelu -> avgpool2 (out bf16) ----
__global__ __launch_bounds__(256) void k_scat_conv1(
    const float* __restrict__ x, const float* __restrict__ w1,
    const float* __restrict__ b1, const float* __restrict__ a1,
    unsigned short* __restrict__ out1, int b0)
{
    __shared__ float img[66 * 66];
    __shared__ float ws[32 * 9];
    __shared__ float bs[32];
    const int t = threadIdx.x;
    const int bl = blockIdx.x;
    const int b = b0 + bl;

    for (int i = t; i < 66 * 66; i += 256) img[i] = 0.0f;
    for (int i = t; i < 288; i += 256) ws[i] = w1[i];
    if (t < 32) bs[t] = b1[t];
    __syncthreads();

    const float* xb = x + (size_t)b * 8192;
    for (int s = t; s < 4096; s += 256) {
        float xi = xb[s];
        float xq = xb[4096 + s];
        int ii = (int)(xi * 16.0f + 32.0f);
        int qi = (int)(xq * 16.0f + 32.0f);
        ii = min(max(ii, 0), 63);
        qi = min(max(qi, 0), 63);
        img[(qi + 1) * 66 + (ii + 1)] = 1.0f;
    }
    __syncthreads();

    const float alpha = a1[0];
    unsigned short* ob = out1 + (size_t)bl * 32 * 1024;
    for (int i = 0; i < 4; ++i) {
        int p = i * 256 + t;
        int py = p >> 5, px = p & 31;
        float v[4][4];
        #pragma unroll
        for (int r = 0; r < 4; ++r)
            #pragma unroll
            for (int c = 0; c < 4; ++c)
                v[r][c] = img[(2 * py + r) * 66 + (2 * px + c)];
        for (int c = 0; c < 32; ++c) {
            float w[9];
            #pragma unroll
            for (int k = 0; k < 9; ++k) w[k] = ws[c * 9 + k];
            float s00 = 0.f, s01 = 0.f, s10 = 0.f, s11 = 0.f;
            #pragma unroll
            for (int ky = 0; ky < 3; ++ky)
                #pragma unroll
                for (int kx = 0; kx < 3; ++kx) {
                    float wk = w[ky * 3 + kx];
                    s00 = fmaf(v[ky][kx],         wk, s00);
                    s01 = fmaf(v[ky][kx + 1],     wk, s01);
                    s10 = fmaf(v[ky + 1][kx],     wk, s10);
                    s11 = fmaf(v[ky + 1][kx + 1], wk, s11);
                }
            float bb = bs[c];
            float o = 0.25f * (prelu(s00 + bb, alpha) + prelu(s01 + bb, alpha) +
                               prelu(s10 + bb, alpha) + prelu(s11 + bb, alpha));
            ob[c * 1024 + p] = bf16_rn(o);
        }
    }
}

// ---------------- Kernel 2: conv2 via bf16 MFMA implicit GEMM ----------------
// block = (image, y-half of 16 out rows). 8 waves = 2 m-pairs x 4 row-quads.
// Per tap (9): D[64co][p] += W[co][32ci] x In[ci][p_shifted]; K=32 = one MFMA k-step.
// LDS in: [cg4][ly18][sx36][i8] bf16, zero-padded halo. out2 bf16 pooled [C,64,16,16].
__global__ __launch_bounds__(512) void k_conv2_mfma(
    const unsigned short* __restrict__ in1, const unsigned short* __restrict__ whi,
    const unsigned short* __restrict__ wlo, const float* __restrict__ b2,
    const float* __restrict__ a2, unsigned short* __restrict__ out2)
{
    __shared__ __align__(16) unsigned short lb[4 * 18 * 36 * 8]; // 41.5 KB
    __shared__ float bs[64];
    const int t = threadIdx.x;
    const int bl = blockIdx.x >> 1;
    const int yb = blockIdx.x & 1;
    const int lane = t & 63;
    const int w = t >> 6;
    const int mp = w >> 2;        // 0..1 -> m-tiles {2mp, 2mp+1}
    const int nq = w & 3;         // 0..3 -> out rows nq*4..nq*4+3 (block-local)
    const int lg = lane >> 4;
    const int lo16 = lane & 15;

    if (t < 64) bs[t] = b2[t];

    const f32x4 zf = {0.f, 0.f, 0.f, 0.f};
    f32x4 acc[2][8];
    #pragma unroll
    for (int m = 0; m < 2; ++m)
        #pragma unroll
        for (int n = 0; n < 8; ++n) acc[m][n] = zf;

    const s16x8 zz = {0, 0, 0, 0, 0, 0, 0, 0};
    for (int idx = t; idx < 2592; idx += 512)
        reinterpret_cast<s16x8*>(lb)[idx] = zz;
    __syncthreads();

    // stage 32ci x 18 rows x 34 cols (bf16 passthrough)
    for (int idx = t; idx < 19584; idx += 512) {
        int ci = idx / 612;
        int r  = idx - ci * 612;
        int ly = r / 34;
        int sx = r - ly * 34;
        int y = yb * 16 + ly - 1;
        int xx = sx - 1;
        if (y >= 0 && y < 32 && xx >= 0 && xx < 32)
            lb[(((ci >> 3) * 18 + ly) * 36 + sx) * 8 + (ci & 7)] =
                in1[(size_t)(bl * 32 + ci) * 1024 + y * 32 + xx];
    }
    __syncthreads();

    #pragma unroll
    for (int tap = 0; tap < 9; ++tap) {
        const int dy = tap / 3, dx = tap - dy * 3;
        const size_t wbase = ((size_t)tap * 4 + lg) * 512 + (size_t)(mp * 32 + lo16) * 8;
        s16x8 ah0 = *reinterpret_cast<const s16x8*>(whi + wbase);
        s16x8 al0 = *reinterpret_cast<const s16x8*>(wlo + wbase);
        s16x8 ah1 = *reinterpret_cast<const s16x8*>(whi + wbase + 128);
        s16x8 al1 = *reinterpret_cast<const s16x8*>(wlo + wbase + 128);
        #pragma unroll
        for (int n = 0; n < 8; ++n) {
            const int rl = n >> 1, xh = n & 1;
            const int ly = nq * 4 + rl + dy;
            const int sx = xh * 16 + lo16 + dx;
            s16x8 bfrag = *reinterpret_cast<const s16x8*>(
                &lb[((lg * 18 + ly) * 36 + sx) * 8]);
            acc[0][n] = __builtin_amdgcn_mfma_f32_16x16x32_bf16(ah0, bfrag, acc[0][n], 0, 0, 0);
            acc[0][n] = __builtin_amdgcn_mfma_f32_16x16x32_bf16(al0, bfrag, acc[0][n], 0, 0, 0);
            acc[1][n] = __builtin_amdgcn_mfma_f32_16x16x32_bf16(ah1, bfrag, acc[1][n], 0, 0, 0);
            acc[1][n] = __builtin_amdgcn_mfma_f32_16x16x32_bf16(al1, bfrag, acc[1][n], 0, 0, 0);
        }
    }

    // bias + prelu + 2x2 pool -> out2 bf16
    const float alpha = a2[0];
    #pragma unroll
    for (int m = 0; m < 2; ++m) {
        const int co = mp * 32 + m * 16 + lg * 4;
        #pragma unroll
        for (int r = 0; r < 4; ++r) {
            const float bb = bs[co + r];
            #pragma unroll
            for (int pr = 0; pr < 2; ++pr) {
                #pragma unroll
                for (int xh = 0; xh < 2; ++xh) {
                    float v0 = acc[m][(pr * 2) * 2 + xh][r] + bb;
                    float v1 = acc[m][(pr * 2 + 1) * 2 + xh][r] + bb;
                    float s = prelu(v0, alpha) + prelu(v1, alpha);
                    s += __shfl_xor(s, 1, 64);
                    if (!(lo16 & 1)) {
                        int gy = yb * 8 + nq * 2 + pr;
                        int gx = xh * 8 + (lo16 >> 1);
                        out2[(size_t)(bl * 64 + co + r) * 256 + gy * 16 + gx] =
                            bf16_rn(0.25f * s);
                    }
                }
            }
        }
    }
}

// ---------------- Kernel 3: conv3 via bf16 MFMA implicit GEMM (in2 bf16) ----------------
__global__ __launch_bounds__(512) void k_conv3_mfma(
    const unsigned short* __restrict__ in2, const unsigned short* __restrict__ whi,
    const unsigned short* __restrict__ wlo, const float* __restrict__ b3,
    const float* __restrict__ a3, float* __restrict__ out3, int b0)
{
    __shared__ __align__(16) unsigned short lb[4 * 12 * 20 * 8];
    __shared__ float bs[128];

    const int t = threadIdx.x;
    const int bl = blockIdx.x >> 1;
    const int yb = blockIdx.x & 1;
    const int lane = t & 63;
    const int w = t >> 6;
    const int mp = w >> 1;
    const int nh = w & 1;
    const int lg = lane >> 4;
    const int lo16 = lane & 15;

    if (t < 128) bs[t] = b3[t];

    const f32x4 zf = {0.f, 0.f, 0.f, 0.f};
    f32x4 acc[2][4];
    #pragma unroll
    for (int m = 0; m < 2; ++m)
        #pragma unroll
        for (int n = 0; n < 4; ++n) acc[m][n] = zf;

    const s16x8 zz = {0, 0, 0, 0, 0, 0, 0, 0};

    for (int kk = 0; kk < 2; ++kk) {
        __syncthreads();
        for (int idx = t; idx < 960; idx += 512)
            reinterpret_cast<s16x8*>(lb)[idx] = zz;
        __syncthreads();
        for (int idx = t; idx < 6144; idx += 512) {
            int x = idx & 15, rest = idx >> 4, ci = rest & 31, ly = rest >> 5;
            int row = yb * 8 + ly - 2;
            if (row >= 0 && row < 16) {
                lb[(((ci >> 3) * 12 + ly) * 20 + (x + 2)) * 8 + (ci & 7)] =
                    in2[((size_t)bl * 64 + kk * 32 + ci) * 256 + row * 16 + x];
            }
        }
        __syncthreads();

        for (int tap = 0; tap < 25; ++tap) {
            int dy = tap / 5, dx = tap - dy * 5;
            const size_t wbase = ((size_t)(tap * 2 + kk) * 4 + lg) * 1024
                               + (size_t)(mp * 32 + lo16) * 8;
            s16x8 ah0 = *reinterpret_cast<const s16x8*>(whi + wbase);
            s16x8 al0 = *reinterpret_cast<const s16x8*>(wlo + wbase);
            s16x8 ah1 = *reinterpret_cast<const s16x8*>(whi + wbase + 128);
            s16x8 al1 = *reinterpret_cast<const s16x8*>(wlo + wbase + 128);
            #pragma unroll
            for (int n = 0; n < 4; ++n) {
                int ly = nh * 4 + n + dy;
                int ax = lo16 + dx;
                s16x8 bfrag = *reinterpret_cast<const s16x8*>(
                    &lb[((lg * 12 + ly) * 20 + ax) * 8]);
                acc[0][n] = __builtin_amdgcn_mfma_f32_16x16x32_bf16(ah0, bfrag, acc[0][n], 0, 0, 0);
                acc[0][n] = __builtin_amdgcn_mfma_f32_16x16x32_bf16(al0, bfrag, acc[0][n], 0, 0, 0);
                acc[1][n] = __builtin_amdgcn_mfma_f32_16x16x32_bf16(ah1, bfrag, acc[1][n], 0, 0, 0);
                acc[1][n] = __builtin_amdgcn_mfma_f32_16x16x32_bf16(al1, bfrag, acc[1][n], 0, 0, 0);
            }
        }
    }

    const float alpha = a3[0];
    const int b = b0 + bl;
    const int fy = yb * 2 + nh;
    const int fx = lo16 >> 2;
    #pragma unroll
    for (int m = 0; m < 2; ++m) {
        const int cobase = mp * 32 + m * 16 + lg * 4;
        #pragma unroll
        for (int r = 0; r < 4; ++r) {
            float bb = bs[cobase + r];
            float s = 0.f;
            #pragma unroll
            for (int n = 0; n < 4; ++n) {
                float v = acc[m][n][r] + bb;
                s += v > 0.f ? v : alpha * v;
            }
            s += __shfl_xor(s, 1, 64);
            s += __shfl_xor(s, 2, 64);
            if ((lane & 3) == 0)
                out3[((size_t)b * 128 + cobase + r) * 16 + fy * 4 + fx] = s * 0.0625f;
        }
    }
}

// ---------------- Kernel 4: fc1(2048->256)+b+prelu, fc2(256->128)+b ----------------
__global__ __launch_bounds__(256) void k_fc(
    const float* __restrict__ h, const float* __restrict__ wc1,
    const float* __restrict__ bc1, const float* __restrict__ ac,
    const float* __restrict__ wc2, const float* __restrict__ bc2,
    float* __restrict__ out)
{
    __shared__ float xr[4][2048];
    __shared__ float hid[4][256];
    const int t = threadIdx.x;
    const int r0 = blockIdx.x * 4;

    for (int idx = t; idx < 4 * 2048; idx += 256) {
        int r = idx >> 11;
        int k = idx & 2047;
        xr[r][k] = h[(size_t)(r0 + r) * 2048 + k];
    }
    __syncthreads();

    {
        float acc[4] = {0.f, 0.f, 0.f, 0.f};
        const float* wp = wc1 + (size_t)t * 2048;
        for (int k = 0; k < 2048; k += 4) {
            float4 w4 = *(const float4*)(wp + k);
            #pragma unroll
            for (int r = 0; r < 4; ++r) {
                acc[r] = fmaf(xr[r][k + 0], w4.x, acc[r]);
                acc[r] = fmaf(xr[r][k + 1], w4.y, acc[r]);
                acc[r] = fmaf(xr[r][k + 2], w4.z, acc[r]);
                acc[r] = fmaf(xr[r][k + 3], w4.w, acc[r]);
            }
        }
        float bb = bc1[t];
        float alpha = ac[0];
        #pragma unroll
        for (int r = 0; r < 4; ++r) hid[r][t] = prelu(acc[r] + bb, alpha);
    }
    __syncthreads();

    {
        const int o = t & 127;
        const int rb = (t >> 7) * 2;
        float acc[2] = {0.f, 0.f};
        const float* wp = wc2 + (size_t)o * 256;
        for (int k = 0; k < 256; k += 4) {
            float4 w4 = *(const float4*)(wp + k);
            #pragma unroll
            for (int rr = 0; rr < 2; ++rr) {
                acc[rr] = fmaf(hid[rb + rr][k + 0], w4.x, acc[rr]);
                acc[rr] = fmaf(hid[rb + rr][k + 1], w4.y, acc[rr]);
                acc[rr] = fmaf(hid[rb + rr][k + 2], w4.z, acc[rr]);
                acc[rr] = fmaf(hid[rb + rr][k + 3], w4.w, acc[rr]);
            }
        }
        float bb = bc2[o];
        out[(size_t)(r0 + rb) * 128 + o] = acc[0] + bb;
        out[(size_t)(r0 + rb + 1) * 128 + o] = acc[1] + bb;
    }
}

extern "C" void kernel_launch(void* const* d_in, const int* in_sizes, int n_in,
                              void* d_out, int out_size, void* d_ws, size_t ws_size,
                              hipStream_t stream) {
    const float* x   = (const float*)d_in[0];
    const float* w1  = (const float*)d_in[1];
    const float* b1  = (const float*)d_in[2];
    const float* a1  = (const float*)d_in[3];
    const float* w2  = (const float*)d_in[4];
    const float* b2  = (const float*)d_in[5];
    const float* a2  = (const float*)d_in[6];
    const float* w3  = (const float*)d_in[7];
    const float* b3  = (const float*)d_in[8];
    const float* a3  = (const float*)d_in[9];
    const float* wc1 = (const float*)d_in[10];
    const float* bc1 = (const float*)d_in[11];
    const float* ac  = (const float*)d_in[12];
    const float* wc2 = (const float*)d_in[13];
    const float* bc2 = (const float*)d_in[14];
    float* out = (float*)d_out;

    const size_t OUT3_BYTES = (size_t)1024 * 128 * 16 * 4;  // 8 MB
    const size_t W3PK = (size_t)204800 * 2;                 // 400 KB each
    const size_t W2PK = (size_t)18432 * 2;                  // 36 KB each
    const size_t FIXED = OUT3_BYTES + 2 * W3PK + 2 * W2PK;
    // per-image scratch (bf16): out1 64KB, out2 32KB
    int C = 1024;
    while (C > 1 && FIXED + (size_t)C * (65536 + 32768) > ws_size) C >>= 1;

    char* p = (char*)d_ws;
    float* out3          = (float*)p;            p += OUT3_BYTES;
    unsigned short* whi3 = (unsigned short*)p;   p += W3PK;
    unsigned short* wlo3 = (unsigned short*)p;   p += W3PK;
    unsigned short* whi2 = (unsigned short*)p;   p += W2PK;
    unsigned short* wlo2 = (unsigned short*)p;   p += W2PK;
    unsigned short* out1 = (unsigned short*)p;   p += (size_t)C * 65536;
    unsigned short* out2 = (unsigned short*)p;

    k_prepack3<<<800, 256, 0, stream>>>(w3, whi3, wlo3);
    k_prepack2<<<72, 256, 0, stream>>>(w2, whi2, wlo2);

    const int nchunk = 1024 / C;
    for (int c = 0; c < nchunk; ++c) {
        int b0 = c * C;
        k_scat_conv1<<<C, 256, 0, stream>>>(x, w1, b1, a1, out1, b0);
        k_conv2_mfma<<<2 * C, 512, 0, stream>>>(out1, whi2, wlo2, b2, a2, out2);
        k_conv3_mfma<<<2 * C, 512, 0, stream>>>(out2, whi3, wlo3, b3, a3, out3, b0);
    }
    k_fc<<<256, 256, 0, stream>>>(out3, wc1, bc1, ac, wc2, bc2, out);
}

// Round 4
// 393.593 us; speedup vs baseline: 5.2449x; 1.1915x over previous
//
#include <hip/hip_runtime.h>

// Constellation CNN. conv2+conv3 bf16 MFMA implicit GEMM, NHWC intermediates.
// ws: [out3 8MB][whi3 400K][wlo3 400K][whi2 36K][wlo2 36K][out1 C*64K][out2 C*32K]

typedef short s16x8 __attribute__((ext_vector_type(8)));
typedef float f32x4 __attribute__((ext_vector_type(4)));
typedef unsigned u32x4 __attribute__((ext_vector_type(4)));
typedef unsigned u32x2 __attribute__((ext_vector_type(2)));

__device__ __forceinline__ float prelu(float v, float a) {
    return v > 0.0f ? v : a * v;
}
__device__ __forceinline__ unsigned short bf16_rn(float x) {
    union { float f; unsigned u; } a; a.f = x;
    unsigned r = a.u + 0x7FFF + ((a.u >> 16) & 1);
    return (unsigned short)(r >> 16);
}
__device__ __forceinline__ float bf16_tof(unsigned short h) {
    union { unsigned u; float f; } a; a.u = (unsigned)h << 16;
    return a.f;
}
__device__ __forceinline__ unsigned pack2(float lo, float hi) {
    return (unsigned)bf16_rn(lo) | ((unsigned)bf16_rn(hi) << 16);
}

// ---------------- Prepack conv3 weights: w3[128co][64ci][25t] -> [t][kk2][g4][co128][i8] ----
__global__ __launch_bounds__(256) void k_prepack3(
    const float* __restrict__ w3, unsigned short* __restrict__ whi,
    unsigned short* __restrict__ wlo)
{
    int e = blockIdx.x * 256 + threadIdx.x;      // 0 .. 204799
    int i  = e & 7;
    int co = (e >> 3) & 127;
    int g  = (e >> 10) & 3;
    int kk = (e >> 12) & 1;
    int tp = e >> 13;
    int ci = kk * 32 + g * 8 + i;
    float w = w3[((size_t)co * 64 + ci) * 25 + tp];
    unsigned short h = bf16_rn(w);
    whi[e] = h;
    wlo[e] = bf16_rn(w - bf16_tof(h));
}

// ---------------- Prepack conv2 weights: w2[64co][32ci][9t] -> [t][g4][co64][i8] ----
__global__ __launch_bounds__(256) void k_prepack2(
    const float* __restrict__ w2, unsigned short* __restrict__ whi,
    unsigned short* __restrict__ wlo)
{
    int e = blockIdx.x * 256 + threadIdx.x;      // 0 .. 18431
    int i  = e & 7;
    int co = (e >> 3) & 63;
    int g  = (e >> 9) & 3;
    int tp = e >> 11;
    int ci = g * 8 + i;
    float w = w2[((size_t)co * 32 + ci) * 9 + tp];
    unsigned short h = bf16_rn(w);
    whi[e] = h;
    wlo[e] = bf16_rn(w - bf16_tof(h));
}

// ---------------- Kernel 1: scatter -> conv1+prelu -> pool. out1 NHWC bf16 [p1024][ci32] ----
__global__ __launch_bounds__(256) void k_scat_conv1(
    const float* __restrict__ x, const float* __restrict__ w1,
    const float* __restrict__ b1, const float* __restrict__ a1,
    unsigned short* __restrict__ out1, int b0)
{
    __shared__ float img[66 * 66];
    __shared__ float ws[32 * 9];
    __shared__ float bs[32];
    const int t = threadIdx.x;
    const int bl = blockIdx.x;
    const int b = b0 + bl;

    for (int i = t; i < 66 * 66; i += 256) img[i] = 0.0f;
    for (int i = t; i < 288; i += 256) ws[i] = w1[i];
    if (t < 32) bs[t] = b1[t];
    __syncthreads();

    const float* xb = x + (size_t)b * 8192;
    for (int s = t; s < 4096; s += 256) {
        float xi = xb[s];
        float xq = xb[4096 + s];
        int ii = (int)(xi * 16.0f + 32.0f);
        int qi = (int)(xq * 16.0f + 32.0f);
        ii = min(max(ii, 0), 63);
        qi = min(max(qi, 0), 63);
        img[(qi + 1) * 66 + (ii + 1)] = 1.0f;
    }
    __syncthreads();

    const float alpha = a1[0];
    unsigned short* ob = out1 + (size_t)bl * 32768;
    for (int i = 0; i < 4; ++i) {
        int p = i * 256 + t;
        int py = p >> 5, px = p & 31;
        float v[4][4];
        #pragma unroll
        for (int r = 0; r < 4; ++r)
            #pragma unroll
            for (int c = 0; c < 4; ++c)
                v[r][c] = img[(2 * py + r) * 66 + (2 * px + c)];
        unsigned pk[16];
        #pragma unroll
        for (int cp = 0; cp < 16; ++cp) {
            float o2[2];
            #pragma unroll
            for (int h = 0; h < 2; ++h) {
                const int c = cp * 2 + h;
                float w[9];
                #pragma unroll
                for (int k = 0; k < 9; ++k) w[k] = ws[c * 9 + k];
                float s00 = 0.f, s01 = 0.f, s10 = 0.f, s11 = 0.f;
                #pragma unroll
                for (int ky = 0; ky < 3; ++ky)
                    #pragma unroll
                    for (int kx = 0; kx < 3; ++kx) {
                        float wk = w[ky * 3 + kx];
                        s00 = fmaf(v[ky][kx],         wk, s00);
                        s01 = fmaf(v[ky][kx + 1],     wk, s01);
                        s10 = fmaf(v[ky + 1][kx],     wk, s10);
                        s11 = fmaf(v[ky + 1][kx + 1], wk, s11);
                    }
                float bb = bs[c];
                o2[h] = 0.25f * (prelu(s00 + bb, alpha) + prelu(s01 + bb, alpha) +
                                 prelu(s10 + bb, alpha) + prelu(s11 + bb, alpha));
            }
            pk[cp] = pack2(o2[0], o2[1]);
        }
        unsigned short* dst = ob + (size_t)p * 32;
        #pragma unroll
        for (int j = 0; j < 4; ++j) {
            u32x4 q = {pk[4 * j], pk[4 * j + 1], pk[4 * j + 2], pk[4 * j + 3]};
            *reinterpret_cast<u32x4*>(dst + j * 8) = q;
        }
    }
}

// ---------------- Kernel 2: conv2 via bf16 MFMA. in1 NHWC [p][ci32], out2 NHWC [p][co64] ----
// block = (image, y-half of 16 out rows). 8 waves = 2 m-pairs x 4 row-quads.
__global__ __launch_bounds__(512) void k_conv2_mfma(
    const unsigned short* __restrict__ in1, const unsigned short* __restrict__ whi,
    const unsigned short* __restrict__ wlo, const float* __restrict__ b2,
    const float* __restrict__ a2, unsigned short* __restrict__ out2)
{
    __shared__ __align__(16) unsigned short lb[4 * 18 * 36 * 8]; // 41.5 KB [cg][ly][sx][i8]
    __shared__ float bs[64];
    const int t = threadIdx.x;
    const int bl = blockIdx.x >> 1;
    const int yb = blockIdx.x & 1;
    const int lane = t & 63;
    const int w = t >> 6;
    const int mp = w >> 2;        // 0..1 -> m-tiles {2mp, 2mp+1}
    const int nq = w & 3;         // 0..3 -> out rows nq*4..nq*4+3 (block-local)
    const int lg = lane >> 4;
    const int lo16 = lane & 15;

    if (t < 64) bs[t] = b2[t];

    const f32x4 zf = {0.f, 0.f, 0.f, 0.f};
    f32x4 acc[2][8];
    #pragma unroll
    for (int m = 0; m < 2; ++m)
        #pragma unroll
        for (int n = 0; n < 8; ++n) acc[m][n] = zf;

    const s16x8 zz = {0, 0, 0, 0, 0, 0, 0, 0};
    for (int idx = t; idx < 2592; idx += 512)
        reinterpret_cast<s16x8*>(lb)[idx] = zz;
    __syncthreads();

    // stage: one lane per pixel (18 rows x 32 cols), 4x b128 load + 4x b128 LDS write
    for (int idx = t; idx < 576; idx += 512) {
        int ly = idx >> 5;
        int xx = idx & 31;
        int y = yb * 16 + ly - 1;
        if (y >= 0 && y < 32) {
            const s16x8* src = reinterpret_cast<const s16x8*>(
                in1 + ((size_t)bl * 1024 + y * 32 + xx) * 32);
            #pragma unroll
            for (int cg = 0; cg < 4; ++cg) {
                *reinterpret_cast<s16x8*>(&lb[((cg * 18 + ly) * 36 + (xx + 1)) * 8]) = src[cg];
            }
        }
    }
    __syncthreads();

    #pragma unroll
    for (int tap = 0; tap < 9; ++tap) {
        const int dy = tap / 3, dx = tap - dy * 3;
        const size_t wbase = ((size_t)tap * 4 + lg) * 512 + (size_t)(mp * 32 + lo16) * 8;
        s16x8 ah0 = *reinterpret_cast<const s16x8*>(whi + wbase);
        s16x8 al0 = *reinterpret_cast<const s16x8*>(wlo + wbase);
        s16x8 ah1 = *reinterpret_cast<const s16x8*>(whi + wbase + 128);
        s16x8 al1 = *reinterpret_cast<const s16x8*>(wlo + wbase + 128);
        #pragma unroll
        for (int n = 0; n < 8; ++n) {
            const int rl = n >> 1, xh = n & 1;
            const int ly = nq * 4 + rl + dy;
            const int sx = xh * 16 + lo16 + dx;
            s16x8 bfrag = *reinterpret_cast<const s16x8*>(
                &lb[((lg * 18 + ly) * 36 + sx) * 8]);
            acc[0][n] = __builtin_amdgcn_mfma_f32_16x16x32_bf16(ah0, bfrag, acc[0][n], 0, 0, 0);
            acc[0][n] = __builtin_amdgcn_mfma_f32_16x16x32_bf16(al0, bfrag, acc[0][n], 0, 0, 0);
            acc[1][n] = __builtin_amdgcn_mfma_f32_16x16x32_bf16(ah1, bfrag, acc[1][n], 0, 0, 0);
            acc[1][n] = __builtin_amdgcn_mfma_f32_16x16x32_bf16(al1, bfrag, acc[1][n], 0, 0, 0);
        }
    }

    // bias + prelu + 2x2 pool -> out2 NHWC bf16, packed 8B stores (4 consecutive co)
    const float alpha = a2[0];
    #pragma unroll
    for (int m = 0; m < 2; ++m) {
        const int co = mp * 32 + m * 16 + lg * 4;
        #pragma unroll
        for (int pr = 0; pr < 2; ++pr) {
            #pragma unroll
            for (int xh = 0; xh < 2; ++xh) {
                float sr[4];
                #pragma unroll
                for (int r = 0; r < 4; ++r) {
                    const float bb = bs[co + r];
                    float v0 = acc[m][(pr * 2) * 2 + xh][r] + bb;
                    float v1 = acc[m][(pr * 2 + 1) * 2 + xh][r] + bb;
                    float s = prelu(v0, alpha) + prelu(v1, alpha);
                    s += __shfl_xor(s, 1, 64);
                    sr[r] = s * 0.25f;
                }
                if (!(lo16 & 1)) {
                    int gy = yb * 8 + nq * 2 + pr;
                    int gx = xh * 8 + (lo16 >> 1);
                    u32x2 q = {pack2(sr[0], sr[1]), pack2(sr[2], sr[3])};
                    *reinterpret_cast<u32x2*>(
                        out2 + ((size_t)bl * 256 + gy * 16 + gx) * 64 + co) = q;
                }
            }
        }
    }
}

// ---------------- Kernel 3: conv3 via bf16 MFMA. in2 NHWC [p256][ci64] ----------------
// block = (image, y-half). LDS holds all 64 ci: [g8][ly12][x20][i8] (30 KB).
__global__ __launch_bounds__(512) void k_conv3_mfma(
    const unsigned short* __restrict__ in2, const unsigned short* __restrict__ whi,
    const unsigned short* __restrict__ wlo, const float* __restrict__ b3,
    const float* __restrict__ a3, float* __restrict__ out3, int b0)
{
    __shared__ __align__(16) unsigned short lb[8 * 12 * 20 * 8]; // 30 KB
    __shared__ float bs[128];

    const int t = threadIdx.x;
    const int bl = blockIdx.x >> 1;
    const int yb = blockIdx.x & 1;
    const int lane = t & 63;
    const int w = t >> 6;
    const int mp = w >> 1;
    const int nh = w & 1;
    const int lg = lane >> 4;
    const int lo16 = lane & 15;

    if (t < 128) bs[t] = b3[t];

    const s16x8 zz = {0, 0, 0, 0, 0, 0, 0, 0};
    for (int idx = t; idx < 1920; idx += 512)
        reinterpret_cast<s16x8*>(lb)[idx] = zz;
    __syncthreads();

    // stage: idx = g*192 + pixel; b128 global load + b128 LDS write (conflict-free)
    for (int idx = t; idx < 1536; idx += 512) {
        int g = idx / 192;
        int pix = idx - g * 192;
        int ly = pix >> 4;
        int xx = pix & 15;
        int row = yb * 8 + ly - 2;
        if (row >= 0 && row < 16) {
            s16x8 v = *reinterpret_cast<const s16x8*>(
                in2 + ((size_t)bl * 256 + row * 16 + xx) * 64 + g * 8);
            *reinterpret_cast<s16x8*>(&lb[((g * 12 + ly) * 20 + (xx + 2)) * 8]) = v;
        }
    }
    __syncthreads();

    const f32x4 zf = {0.f, 0.f, 0.f, 0.f};
    f32x4 acc[2][4];
    #pragma unroll
    for (int m = 0; m < 2; ++m)
        #pragma unroll
        for (int n = 0; n < 4; ++n) acc[m][n] = zf;

    for (int kk = 0; kk < 2; ++kk) {
        for (int tap = 0; tap < 25; ++tap) {
            int dy = tap / 5, dx = tap - dy * 5;
            const size_t wbase = ((size_t)(tap * 2 + kk) * 4 + lg) * 1024
                               + (size_t)(mp * 32 + lo16) * 8;
            s16x8 ah0 = *reinterpret_cast<const s16x8*>(whi + wbase);
            s16x8 al0 = *reinterpret_cast<const s16x8*>(wlo + wbase);
            s16x8 ah1 = *reinterpret_cast<const s16x8*>(whi + wbase + 128);
            s16x8 al1 = *reinterpret_cast<const s16x8*>(wlo + wbase + 128);
            #pragma unroll
            for (int n = 0; n < 4; ++n) {
                int ly = nh * 4 + n + dy;
                int ax = lo16 + dx;
                s16x8 bfrag = *reinterpret_cast<const s16x8*>(
                    &lb[(((kk * 4 + lg) * 12 + ly) * 20 + ax) * 8]);
                acc[0][n] = __builtin_amdgcn_mfma_f32_16x16x32_bf16(ah0, bfrag, acc[0][n], 0, 0, 0);
                acc[0][n] = __builtin_amdgcn_mfma_f32_16x16x32_bf16(al0, bfrag, acc[0][n], 0, 0, 0);
                acc[1][n] = __builtin_amdgcn_mfma_f32_16x16x32_bf16(ah1, bfrag, acc[1][n], 0, 0, 0);
                acc[1][n] = __builtin_amdgcn_mfma_f32_16x16x32_bf16(al1, bfrag, acc[1][n], 0, 0, 0);
            }
        }
    }

    const float alpha = a3[0];
    const int b = b0 + bl;
    const int fy = yb * 2 + nh;
    const int fx = lo16 >> 2;
    #pragma unroll
    for (int m = 0; m < 2; ++m) {
        const int cobase = mp * 32 + m * 16 + lg * 4;
        #pragma unroll
        for (int r = 0; r < 4; ++r) {
            float bb = bs[cobase + r];
            float s = 0.f;
            #pragma unroll
            for (int n = 0; n < 4; ++n) {
                float v = acc[m][n][r] + bb;
                s += v > 0.f ? v : alpha * v;
            }
            s += __shfl_xor(s, 1, 64);
            s += __shfl_xor(s, 2, 64);
            if ((lane & 3) == 0)
                out3[((size_t)b * 128 + cobase + r) * 16 + fy * 4 + fx] = s * 0.0625f;
        }
    }
}

// ---------------- Kernel 4: fc1(2048->256)+b+prelu, fc2(256->128)+b ----------------
// 128 blocks x 8 batch rows, 256 threads.
__global__ __launch_bounds__(256) void k_fc(
    const float* __restrict__ h, const float* __restrict__ wc1,
    const float* __restrict__ bc1, const float* __restrict__ ac,
    const float* __restrict__ wc2, const float* __restrict__ bc2,
    float* __restrict__ out)
{
    __shared__ float xr[8][2048];  // 64 KB
    __shared__ float hid[8][256];  // 8 KB
    const int t = threadIdx.x;
    const int r0 = blockIdx.x * 8;

    for (int idx = t; idx < 4096; idx += 256) {
        int r = idx >> 9;
        int k4 = idx & 511;
        *reinterpret_cast<float4*>(&xr[r][k4 * 4]) =
            *reinterpret_cast<const float4*>(h + (size_t)(r0 + r) * 2048 + k4 * 4);
    }
    __syncthreads();

    {
        float acc[8] = {0.f, 0.f, 0.f, 0.f, 0.f, 0.f, 0.f, 0.f};
        const float* wp = wc1 + (size_t)t * 2048;
        for (int k = 0; k < 2048; k += 4) {
            float4 w4 = *(const float4*)(wp + k);
            #pragma unroll
            for (int r = 0; r < 8; ++r) {
                acc[r] = fmaf(xr[r][k + 0], w4.x, acc[r]);
                acc[r] = fmaf(xr[r][k + 1], w4.y, acc[r]);
                acc[r] = fmaf(xr[r][k + 2], w4.z, acc[r]);
                acc[r] = fmaf(xr[r][k + 3], w4.w, acc[r]);
            }
        }
        float bb = bc1[t];
        float alpha = ac[0];
        #pragma unroll
        for (int r = 0; r < 8; ++r) hid[r][t] = prelu(acc[r] + bb, alpha);
    }
    __syncthreads();

    {
        const int o = t & 127;
        const int rb = (t >> 7) * 4;
        float acc[4] = {0.f, 0.f, 0.f, 0.f};
        const float* wp = wc2 + (size_t)o * 256;
        for (int k = 0; k < 256; k += 4) {
            float4 w4 = *(const float4*)(wp + k);
            #pragma unroll
            for (int rr = 0; rr < 4; ++rr) {
                acc[rr] = fmaf(hid[rb + rr][k + 0], w4.x, acc[rr]);
                acc[rr] = fmaf(hid[rb + rr][k + 1], w4.y, acc[rr]);
                acc[rr] = fmaf(hid[rb + rr][k + 2], w4.z, acc[rr]);
                acc[rr] = fmaf(hid[rb + rr][k + 3], w4.w, acc[rr]);
            }
        }
        float bb = bc2[o];
        #pragma unroll
        for (int rr = 0; rr < 4; ++rr)
            out[(size_t)(r0 + rb + rr) * 128 + o] = acc[rr] + bb;
    }
}

extern "C" void kernel_launch(void* const* d_in, const int* in_sizes, int n_in,
                              void* d_out, int out_size, void* d_ws, size_t ws_size,
                              hipStream_t stream) {
    const float* x   = (const float*)d_in[0];
    const float* w1  = (const float*)d_in[1];
    const float* b1  = (const float*)d_in[2];
    const float* a1  = (const float*)d_in[3];
    const float* w2  = (const float*)d_in[4];
    const float* b2  = (const float*)d_in[5];
    const float* a2  = (const float*)d_in[6];
    const float* w3  = (const float*)d_in[7];
    const float* b3  = (const float*)d_in[8];
    const float* a3  = (const float*)d_in[9];
    const float* wc1 = (const float*)d_in[10];
    const float* bc1 = (const float*)d_in[11];
    const float* ac  = (const float*)d_in[12];
    const float* wc2 = (const float*)d_in[13];
    const float* bc2 = (const float*)d_in[14];
    float* out = (float*)d_out;

    const size_t OUT3_BYTES = (size_t)1024 * 128 * 16 * 4;  // 8 MB
    const size_t W3PK = (size_t)204800 * 2;                 // 400 KB each
    const size_t W2PK = (size_t)18432 * 2;                  // 36 KB each
    const size_t FIXED = OUT3_BYTES + 2 * W3PK + 2 * W2PK;
    int C = 1024;
    while (C > 1 && FIXED + (size_t)C * (65536 + 32768) > ws_size) C >>= 1;

    char* p = (char*)d_ws;
    float* out3          = (float*)p;            p += OUT3_BYTES;
    unsigned short* whi3 = (unsigned short*)p;   p += W3PK;
    unsigned short* wlo3 = (unsigned short*)p;   p += W3PK;
    unsigned short* whi2 = (unsigned short*)p;   p += W2PK;
    unsigned short* wlo2 = (unsigned short*)p;   p += W2PK;
    unsigned short* out1 = (unsigned short*)p;   p += (size_t)C * 65536;
    unsigned short* out2 = (unsigned short*)p;

    k_prepack3<<<800, 256, 0, stream>>>(w3, whi3, wlo3);
    k_prepack2<<<72, 256, 0, stream>>>(w2, whi2, wlo2);

    const int nchunk = 1024 / C;
    for (int c = 0; c < nchunk; ++c) {
        int b0 = c * C;
        k_scat_conv1<<<C, 256, 0, stream>>>(x, w1, b1, a1, out1, b0);
        k_conv2_mfma<<<2 * C, 512, 0, stream>>>(out1, whi2, wlo2, b2, a2, out2);
        k_conv3_mfma<<<2 * C, 512, 0, stream>>>(out2, whi3, wlo3, b3, a3, out3, b0);
    }
    k_fc<<<128, 256, 0, stream>>>(out3, wc1, bc1, ac, wc2, bc2, out);
}

// Round 5
// 288.906 us; speedup vs baseline: 7.1455x; 1.3624x over previous
//
#include <hip/hip_runtime.h>

// Constellation CNN. conv2+conv3 bf16 MFMA implicit GEMM (single-term bf16 weights),
// NHWC intermediates. ws: [out3 8MB][w3pk 400K][w2pk 36K][out1 C*64K][out2 C*32K]

typedef short s16x8 __attribute__((ext_vector_type(8)));
typedef float f32x4 __attribute__((ext_vector_type(4)));
typedef unsigned u32x4 __attribute__((ext_vector_type(4)));
typedef unsigned u32x2 __attribute__((ext_vector_type(2)));

__device__ __forceinline__ float prelu(float v, float a) {
    return v > 0.0f ? v : a * v;
}
__device__ __forceinline__ unsigned short bf16_rn(float x) {
    union { float f; unsigned u; } a; a.f = x;
    unsigned r = a.u + 0x7FFF + ((a.u >> 16) & 1);
    return (unsigned short)(r >> 16);
}
__device__ __forceinline__ unsigned pack2(float lo, float hi) {
    return (unsigned)bf16_rn(lo) | ((unsigned)bf16_rn(hi) << 16);
}

// ---------------- Prepack conv3 weights: w3[128co][64ci][25t] -> [t][kk2][g4][co128][i8] ----
__global__ __launch_bounds__(256) void k_prepack3(
    const float* __restrict__ w3, unsigned short* __restrict__ wpk)
{
    int e = blockIdx.x * 256 + threadIdx.x;      // 0 .. 204799
    int i  = e & 7;
    int co = (e >> 3) & 127;
    int g  = (e >> 10) & 3;
    int kk = (e >> 12) & 1;
    int tp = e >> 13;
    int ci = kk * 32 + g * 8 + i;
    wpk[e] = bf16_rn(w3[((size_t)co * 64 + ci) * 25 + tp]);
}

// ---------------- Prepack conv2 weights: w2[64co][32ci][9t] -> [t][g4][co64][i8] ----
__global__ __launch_bounds__(256) void k_prepack2(
    const float* __restrict__ w2, unsigned short* __restrict__ wpk)
{
    int e = blockIdx.x * 256 + threadIdx.x;      // 0 .. 18431
    int i  = e & 7;
    int co = (e >> 3) & 63;
    int g  = (e >> 9) & 3;
    int tp = e >> 11;
    int ci = g * 8 + i;
    wpk[e] = bf16_rn(w2[((size_t)co * 32 + ci) * 9 + tp]);
}

// ---------------- Kernel 1: scatter -> conv1+prelu -> pool. out1 NHWC bf16 [p1024][ci32] ----
__global__ __launch_bounds__(256) void k_scat_conv1(
    const float* __restrict__ x, const float* __restrict__ w1,
    const float* __restrict__ b1, const float* __restrict__ a1,
    unsigned short* __restrict__ out1, int b0)
{
    __shared__ float img[66 * 66];
    __shared__ float ws[32 * 9];
    __shared__ float bs[32];
    const int t = threadIdx.x;
    const int bl = blockIdx.x;
    const int b = b0 + bl;

    for (int i = t; i < 66 * 66; i += 256) img[i] = 0.0f;
    for (int i = t; i < 288; i += 256) ws[i] = w1[i];
    if (t < 32) bs[t] = b1[t];
    __syncthreads();

    const float* xb = x + (size_t)b * 8192;
    for (int s = t; s < 4096; s += 256) {
        float xi = xb[s];
        float xq = xb[4096 + s];
        int ii = (int)(xi * 16.0f + 32.0f);
        int qi = (int)(xq * 16.0f + 32.0f);
        ii = min(max(ii, 0), 63);
        qi = min(max(qi, 0), 63);
        img[(qi + 1) * 66 + (ii + 1)] = 1.0f;
    }
    __syncthreads();

    const float alpha = a1[0];
    unsigned short* ob = out1 + (size_t)bl * 32768;
    for (int i = 0; i < 4; ++i) {
        int p = i * 256 + t;
        int py = p >> 5, px = p & 31;
        float v[4][4];
        #pragma unroll
        for (int r = 0; r < 4; ++r)
            #pragma unroll
            for (int c = 0; c < 4; ++c)
                v[r][c] = img[(2 * py + r) * 66 + (2 * px + c)];
        unsigned pk[16];
        #pragma unroll
        for (int cp = 0; cp < 16; ++cp) {
            float o2[2];
            #pragma unroll
            for (int h = 0; h < 2; ++h) {
                const int c = cp * 2 + h;
                float w[9];
                #pragma unroll
                for (int k = 0; k < 9; ++k) w[k] = ws[c * 9 + k];
                float s00 = 0.f, s01 = 0.f, s10 = 0.f, s11 = 0.f;
                #pragma unroll
                for (int ky = 0; ky < 3; ++ky)
                    #pragma unroll
                    for (int kx = 0; kx < 3; ++kx) {
                        float wk = w[ky * 3 + kx];
                        s00 = fmaf(v[ky][kx],         wk, s00);
                        s01 = fmaf(v[ky][kx + 1],     wk, s01);
                        s10 = fmaf(v[ky + 1][kx],     wk, s10);
                        s11 = fmaf(v[ky + 1][kx + 1], wk, s11);
                    }
                float bb = bs[c];
                o2[h] = 0.25f * (prelu(s00 + bb, alpha) + prelu(s01 + bb, alpha) +
                                 prelu(s10 + bb, alpha) + prelu(s11 + bb, alpha));
            }
            pk[cp] = pack2(o2[0], o2[1]);
        }
        unsigned short* dst = ob + (size_t)p * 32;
        #pragma unroll
        for (int j = 0; j < 4; ++j) {
            u32x4 q = {pk[4 * j], pk[4 * j + 1], pk[4 * j + 2], pk[4 * j + 3]};
            *reinterpret_cast<u32x4*>(dst + j * 8) = q;
        }
    }
}

// ---------------- Kernel 2: conv2 via bf16 MFMA. in1 NHWC [p][ci32], out2 NHWC [p][co64] ----
// block = (image, y-half of 16 out rows). 8 waves = 2 m-pairs x 4 row-quads.
__global__ __launch_bounds__(512) void k_conv2_mfma(
    const unsigned short* __restrict__ in1, const unsigned short* __restrict__ wpk,
    const float* __restrict__ b2, const float* __restrict__ a2,
    unsigned short* __restrict__ out2)
{
    __shared__ __align__(16) unsigned short lb[4 * 18 * 36 * 8]; // 41.5 KB [cg][ly][sx][i8]
    __shared__ float bs[64];
    const int t = threadIdx.x;
    const int bl = blockIdx.x >> 1;
    const int yb = blockIdx.x & 1;
    const int lane = t & 63;
    const int w = t >> 6;
    const int mp = w >> 2;        // 0..1 -> m-tiles {2mp, 2mp+1}
    const int nq = w & 3;         // 0..3 -> out rows nq*4..nq*4+3 (block-local)
    const int lg = lane >> 4;
    const int lo16 = lane & 15;

    if (t < 64) bs[t] = b2[t];

    const f32x4 zf = {0.f, 0.f, 0.f, 0.f};
    f32x4 acc[2][8];
    #pragma unroll
    for (int m = 0; m < 2; ++m)
        #pragma unroll
        for (int n = 0; n < 8; ++n) acc[m][n] = zf;

    const s16x8 zz = {0, 0, 0, 0, 0, 0, 0, 0};
    for (int idx = t; idx < 2592; idx += 512)
        reinterpret_cast<s16x8*>(lb)[idx] = zz;
    __syncthreads();

    // stage: one lane per pixel (18 rows x 32 cols), 4x b128 load + 4x b128 LDS write
    for (int idx = t; idx < 576; idx += 512) {
        int ly = idx >> 5;
        int xx = idx & 31;
        int y = yb * 16 + ly - 1;
        if (y >= 0 && y < 32) {
            const s16x8* src = reinterpret_cast<const s16x8*>(
                in1 + ((size_t)bl * 1024 + y * 32 + xx) * 32);
            #pragma unroll
            for (int cg = 0; cg < 4; ++cg) {
                *reinterpret_cast<s16x8*>(&lb[((cg * 18 + ly) * 36 + (xx + 1)) * 8]) = src[cg];
            }
        }
    }
    __syncthreads();

    #pragma unroll
    for (int tap = 0; tap < 9; ++tap) {
        const int dy = tap / 3, dx = tap - dy * 3;
        const size_t wbase = ((size_t)tap * 4 + lg) * 512 + (size_t)(mp * 32 + lo16) * 8;
        s16x8 a0 = *reinterpret_cast<const s16x8*>(wpk + wbase);
        s16x8 a1 = *reinterpret_cast<const s16x8*>(wpk + wbase + 128);
        #pragma unroll
        for (int n = 0; n < 8; ++n) {
            const int rl = n >> 1, xh = n & 1;
            const int ly = nq * 4 + rl + dy;
            const int sx = xh * 16 + lo16 + dx;
            s16x8 bfrag = *reinterpret_cast<const s16x8*>(
                &lb[((lg * 18 + ly) * 36 + sx) * 8]);
            acc[0][n] = __builtin_amdgcn_mfma_f32_16x16x32_bf16(a0, bfrag, acc[0][n], 0, 0, 0);
            acc[1][n] = __builtin_amdgcn_mfma_f32_16x16x32_bf16(a1, bfrag, acc[1][n], 0, 0, 0);
        }
    }

    // bias + prelu + 2x2 pool -> out2 NHWC bf16, packed 8B stores (4 consecutive co)
    const float alpha = a2[0];
    #pragma unroll
    for (int m = 0; m < 2; ++m) {
        const int co = mp * 32 + m * 16 + lg * 4;
        #pragma unroll
        for (int pr = 0; pr < 2; ++pr) {
            #pragma unroll
            for (int xh = 0; xh < 2; ++xh) {
                float sr[4];
                #pragma unroll
                for (int r = 0; r < 4; ++r) {
                    const float bb = bs[co + r];
                    float v0 = acc[m][(pr * 2) * 2 + xh][r] + bb;
                    float v1 = acc[m][(pr * 2 + 1) * 2 + xh][r] + bb;
                    float s = prelu(v0, alpha) + prelu(v1, alpha);
                    s += __shfl_xor(s, 1, 64);
                    sr[r] = s * 0.25f;
                }
                if (!(lo16 & 1)) {
                    int gy = yb * 8 + nq * 2 + pr;
                    int gx = xh * 8 + (lo16 >> 1);
                    u32x2 q = {pack2(sr[0], sr[1]), pack2(sr[2], sr[3])};
                    *reinterpret_cast<u32x2*>(
                        out2 + ((size_t)bl * 256 + gy * 16 + gx) * 64 + co) = q;
                }
            }
        }
    }
}

// ---------------- Kernel 3: conv3 via bf16 MFMA. in2 NHWC [p256][ci64], full image/block ----
// LDS [g8][ly20][ax20][i8] = 51.2 KB. 8 waves = 4 m-pairs x 2 row-halves (8 rows each).
__global__ __launch_bounds__(512) void k_conv3_mfma(
    const unsigned short* __restrict__ in2, const unsigned short* __restrict__ wpk,
    const float* __restrict__ b3, const float* __restrict__ a3,
    float* __restrict__ out3, int b0)
{
    __shared__ __align__(16) unsigned short lb[8 * 20 * 20 * 8]; // 51.2 KB
    __shared__ float bs[128];

    const int t = threadIdx.x;
    const int bl = blockIdx.x;
    const int lane = t & 63;
    const int w = t >> 6;
    const int mp = w >> 1;        // 0..3 -> m-tiles {2mp, 2mp+1}
    const int nh = w & 1;         // 0..1 -> pre-pool rows nh*8 .. nh*8+7
    const int lg = lane >> 4;
    const int lo16 = lane & 15;

    if (t < 128) bs[t] = b3[t];

    const s16x8 zz = {0, 0, 0, 0, 0, 0, 0, 0};
    for (int idx = t; idx < 3200; idx += 512)
        reinterpret_cast<s16x8*>(lb)[idx] = zz;
    __syncthreads();

    // stage all 64 ci x 16x16 pixels: b128 load + b128 LDS write (pix-minor: conflict-free)
    for (int idx = t; idx < 2048; idx += 512) {
        int g = idx >> 8;
        int pix = idx & 255;
        int row = pix >> 4;
        int xx = pix & 15;
        s16x8 v = *reinterpret_cast<const s16x8*>(
            in2 + ((size_t)bl * 256 + row * 16 + xx) * 64 + g * 8);
        *reinterpret_cast<s16x8*>(&lb[((g * 20 + (row + 2)) * 20 + (xx + 2)) * 8]) = v;
    }
    __syncthreads();

    const f32x4 zf = {0.f, 0.f, 0.f, 0.f};
    f32x4 acc[2][8];
    #pragma unroll
    for (int m = 0; m < 2; ++m)
        #pragma unroll
        for (int n = 0; n < 8; ++n) acc[m][n] = zf;

    for (int kk = 0; kk < 2; ++kk) {
        for (int tap = 0; tap < 25; ++tap) {
            int dy = tap / 5, dx = tap - dy * 5;
            const size_t wbase = ((size_t)(tap * 2 + kk) * 4 + lg) * 1024
                               + (size_t)(mp * 32 + lo16) * 8;
            s16x8 a0 = *reinterpret_cast<const s16x8*>(wpk + wbase);
            s16x8 a1 = *reinterpret_cast<const s16x8*>(wpk + wbase + 128);
            #pragma unroll
            for (int n = 0; n < 8; ++n) {
                int ly = nh * 8 + n + dy;          // 0..19
                int ax = lo16 + dx;                // 0..19
                s16x8 bfrag = *reinterpret_cast<const s16x8*>(
                    &lb[(((kk * 4 + lg) * 20 + ly) * 20 + ax) * 8]);
                acc[0][n] = __builtin_amdgcn_mfma_f32_16x16x32_bf16(a0, bfrag, acc[0][n], 0, 0, 0);
                acc[1][n] = __builtin_amdgcn_mfma_f32_16x16x32_bf16(a1, bfrag, acc[1][n], 0, 0, 0);
            }
        }
    }

    // bias + prelu + 4x4 mean -> out3[b][co][fy][fx]
    const float alpha = a3[0];
    const int b = b0 + bl;
    const int fx = lo16 >> 2;
    #pragma unroll
    for (int m = 0; m < 2; ++m) {
        const int cobase = mp * 32 + m * 16 + lg * 4;
        #pragma unroll
        for (int r = 0; r < 4; ++r) {
            float bb = bs[cobase + r];
            #pragma unroll
            for (int half = 0; half < 2; ++half) {
                float s = 0.f;
                #pragma unroll
                for (int j = 0; j < 4; ++j) {
                    float v = acc[m][half * 4 + j][r] + bb;
                    s += v > 0.f ? v : alpha * v;
                }
                s += __shfl_xor(s, 1, 64);
                s += __shfl_xor(s, 2, 64);
                if ((lane & 3) == 0) {
                    int fy = nh * 2 + half;
                    out3[((size_t)b * 128 + cobase + r) * 16 + fy * 4 + fx] = s * 0.0625f;
                }
            }
        }
    }
}

// ---------------- Kernel 4: fc1(2048->256)+b+prelu, fc2(256->128)+b ----------------
// 128 blocks x 8 batch rows, 256 threads.
__global__ __launch_bounds__(256) void k_fc(
    const float* __restrict__ h, const float* __restrict__ wc1,
    const float* __restrict__ bc1, const float* __restrict__ ac,
    const float* __restrict__ wc2, const float* __restrict__ bc2,
    float* __restrict__ out)
{
    __shared__ float xr[8][2048];  // 64 KB
    __shared__ float hid[8][256];  // 8 KB
    const int t = threadIdx.x;
    const int r0 = blockIdx.x * 8;

    for (int idx = t; idx < 4096; idx += 256) {
        int r = idx >> 9;
        int k4 = idx & 511;
        *reinterpret_cast<float4*>(&xr[r][k4 * 4]) =
            *reinterpret_cast<const float4*>(h + (size_t)(r0 + r) * 2048 + k4 * 4);
    }
    __syncthreads();

    {
        float acc[8] = {0.f, 0.f, 0.f, 0.f, 0.f, 0.f, 0.f, 0.f};
        const float* wp = wc1 + (size_t)t * 2048;
        for (int k = 0; k < 2048; k += 4) {
            float4 w4 = *(const float4*)(wp + k);
            #pragma unroll
            for (int r = 0; r < 8; ++r) {
                acc[r] = fmaf(xr[r][k + 0], w4.x, acc[r]);
                acc[r] = fmaf(xr[r][k + 1], w4.y, acc[r]);
                acc[r] = fmaf(xr[r][k + 2], w4.z, acc[r]);
                acc[r] = fmaf(xr[r][k + 3], w4.w, acc[r]);
            }
        }
        float bb = bc1[t];
        float alpha = ac[0];
        #pragma unroll
        for (int r = 0; r < 8; ++r) hid[r][t] = prelu(acc[r] + bb, alpha);
    }
    __syncthreads();

    {
        const int o = t & 127;
        const int rb = (t >> 7) * 4;
        float acc[4] = {0.f, 0.f, 0.f, 0.f};
        const float* wp = wc2 + (size_t)o * 256;
        for (int k = 0; k < 256; k += 4) {
            float4 w4 = *(const float4*)(wp + k);
            #pragma unroll
            for (int rr = 0; rr < 4; ++rr) {
                acc[rr] = fmaf(hid[rb + rr][k + 0], w4.x, acc[rr]);
                acc[rr] = fmaf(hid[rb + rr][k + 1], w4.y, acc[rr]);
                acc[rr] = fmaf(hid[rb + rr][k + 2], w4.z, acc[rr]);
                acc[rr] = fmaf(hid[rb + rr][k + 3], w4.w, acc[rr]);
            }
        }
        float bb = bc2[o];
        #pragma unroll
        for (int rr = 0; rr < 4; ++rr)
            out[(size_t)(r0 + rb + rr) * 128 + o] = acc[rr] + bb;
    }
}

extern "C" void kernel_launch(void* const* d_in, const int* in_sizes, int n_in,
                              void* d_out, int out_size, void* d_ws, size_t ws_size,
                              hipStream_t stream) {
    const float* x   = (const float*)d_in[0];
    const float* w1  = (const float*)d_in[1];
    const float* b1  = (const float*)d_in[2];
    const float* a1  = (const float*)d_in[3];
    const float* w2  = (const float*)d_in[4];
    const float* b2  = (const float*)d_in[5];
    const float* a2  = (const float*)d_in[6];
    const float* w3  = (const float*)d_in[7];
    const float* b3  = (const float*)d_in[8];
    const float* a3  = (const float*)d_in[9];
    const float* wc1 = (const float*)d_in[10];
    const float* bc1 = (const float*)d_in[11];
    const float* ac  = (const float*)d_in[12];
    const float* wc2 = (const float*)d_in[13];
    const float* bc2 = (const float*)d_in[14];
    float* out = (float*)d_out;

    const size_t OUT3_BYTES = (size_t)1024 * 128 * 16 * 4;  // 8 MB
    const size_t W3PK = (size_t)204800 * 2;                 // 400 KB
    const size_t W2PK = (size_t)18432 * 2;                  // 36 KB
    const size_t FIXED = OUT3_BYTES + W3PK + W2PK;
    int C = 1024;
    while (C > 1 && FIXED + (size_t)C * (65536 + 32768) > ws_size) C >>= 1;

    char* p = (char*)d_ws;
    float* out3          = (float*)p;            p += OUT3_BYTES;
    unsigned short* w3pk = (unsigned short*)p;   p += W3PK;
    unsigned short* w2pk = (unsigned short*)p;   p += W2PK;
    unsigned short* out1 = (unsigned short*)p;   p += (size_t)C * 65536;
    unsigned short* out2 = (unsigned short*)p;

    k_prepack3<<<800, 256, 0, stream>>>(w3, w3pk);
    k_prepack2<<<72, 256, 0, stream>>>(w2, w2pk);

    const int nchunk = 1024 / C;
    for (int c = 0; c < nchunk; ++c) {
        int b0 = c * C;
        k_scat_conv1<<<C, 256, 0, stream>>>(x, w1, b1, a1, out1, b0);
        k_conv2_mfma<<<2 * C, 512, 0, stream>>>(out1, w2pk, b2, a2, out2);
        k_conv3_mfma<<<C, 512, 0, stream>>>(out2, w3pk, b3, a3, out3, b0);
    }
    k_fc<<<128, 256, 0, stream>>>(out3, wc1, bc1, ac, wc2, bc2, out);
}

// Round 6
// 256.003 us; speedup vs baseline: 8.0638x; 1.1285x over previous
//
#include <hip/hip_runtime.h>

// Constellation CNN. conv2/conv3/fc1/fc2 all bf16 MFMA implicit GEMM.
// NHWC intermediates, out3 bf16 in fc1 B-layout.
// ws: [out3h 4MB][w3pk 400K][w2pk 36K][w1pk(fc1) 1MB][wc2pk 64K][out1 C*64K][out2 C*32K]

typedef short s16x8 __attribute__((ext_vector_type(8)));
typedef float f32x4 __attribute__((ext_vector_type(4)));
typedef unsigned u32x4 __attribute__((ext_vector_type(4)));
typedef unsigned u32x2 __attribute__((ext_vector_type(2)));

__device__ __forceinline__ float prelu(float v, float a) {
    return v > 0.0f ? v : a * v;
}
__device__ __forceinline__ unsigned short bf16_rn(float x) {
    union { float f; unsigned u; } a; a.f = x;
    unsigned r = a.u + 0x7FFF + ((a.u >> 16) & 1);
    return (unsigned short)(r >> 16);
}
__device__ __forceinline__ unsigned pack2(float lo, float hi) {
    return (unsigned)bf16_rn(lo) | ((unsigned)bf16_rn(hi) << 16);
}

// ---------------- Prepack conv3 weights: w3[128co][64ci][25t] -> [t][kk2][g4][co128][i8] ----
__global__ __launch_bounds__(256) void k_prepack3(
    const float* __restrict__ w3, unsigned short* __restrict__ wpk)
{
    int e = blockIdx.x * 256 + threadIdx.x;      // 0 .. 204799
    int i  = e & 7;
    int co = (e >> 3) & 127;
    int g  = (e >> 10) & 3;
    int kk = (e >> 12) & 1;
    int tp = e >> 13;
    int ci = kk * 32 + g * 8 + i;
    wpk[e] = bf16_rn(w3[((size_t)co * 64 + ci) * 25 + tp]);
}

// ---------------- Prepack conv2 weights: w2[64co][32ci][9t] -> [t][g4][co64][i8] ----
__global__ __launch_bounds__(256) void k_prepack2(
    const float* __restrict__ w2, unsigned short* __restrict__ wpk)
{
    int e = blockIdx.x * 256 + threadIdx.x;      // 0 .. 18431
    int i  = e & 7;
    int co = (e >> 3) & 63;
    int g  = (e >> 9) & 3;
    int tp = e >> 11;
    int ci = g * 8 + i;
    wpk[e] = bf16_rn(w2[((size_t)co * 32 + ci) * 9 + tp]);
}

// ---------------- Prepack fc1 weights: wc1[256hid][2048k] -> [kc64][g4][hid256][i8] ----
__global__ __launch_bounds__(256) void k_prepack_fc1(
    const float* __restrict__ wc1, unsigned short* __restrict__ wpk)
{
    int e = blockIdx.x * 256 + threadIdx.x;      // 0 .. 524287
    int i   = e & 7;
    int hid = (e >> 3) & 255;
    int g   = (e >> 11) & 3;
    int kc  = e >> 13;
    int k = kc * 32 + g * 8 + i;
    wpk[e] = bf16_rn(wc1[(size_t)hid * 2048 + k]);
}

// ---------------- Prepack fc2 weights: wc2[128o][256k] -> [kc8][g4][o128][i8] ----
__global__ __launch_bounds__(256) void k_prepack_fc2(
    const float* __restrict__ wc2, unsigned short* __restrict__ wpk)
{
    int e = blockIdx.x * 256 + threadIdx.x;      // 0 .. 32767
    int i  = e & 7;
    int o  = (e >> 3) & 127;
    int g  = (e >> 10) & 3;
    int kc = e >> 12;
    int k = kc * 32 + g * 8 + i;
    wpk[e] = bf16_rn(wc2[(size_t)o * 256 + k]);
}

// ---------------- Kernel 1: scatter -> conv1+prelu -> pool. out1 NHWC bf16 [p1024][ci32] ----
// grid 2*C: (image, y-half). Each block re-scatters all points, keeps its 34-row strip.
__global__ __launch_bounds__(256) void k_scat_conv1(
    const float* __restrict__ x, const float* __restrict__ w1,
    const float* __restrict__ b1, const float* __restrict__ a1,
    unsigned short* __restrict__ out1, int b0)
{
    __shared__ float img[34 * 66];   // pre-pool rows yb*32-1 .. yb*32+32, cols with +1 halo
    __shared__ float ws[32 * 9];
    __shared__ float bs[32];
    const int t = threadIdx.x;
    const int bl = blockIdx.x >> 1;
    const int yb = blockIdx.x & 1;
    const int b = b0 + bl;

    for (int i = t; i < 34 * 66; i += 256) img[i] = 0.0f;
    for (int i = t; i < 288; i += 256) ws[i] = w1[i];
    if (t < 32) bs[t] = b1[t];
    __syncthreads();

    const float* xb = x + (size_t)b * 8192;
    const int rbase = yb * 32 - 1;
    for (int s = t; s < 4096; s += 256) {
        float xi = xb[s];
        float xq = xb[4096 + s];
        int ii = (int)(xi * 16.0f + 32.0f);
        int qi = (int)(xq * 16.0f + 32.0f);
        ii = min(max(ii, 0), 63);
        qi = min(max(qi, 0), 63);
        int r = qi - rbase;
        if (r >= 0 && r < 34) img[r * 66 + (ii + 1)] = 1.0f;
    }
    __syncthreads();

    const float alpha = a1[0];
    unsigned short* ob = out1 + (size_t)bl * 32768;
    for (int i = 0; i < 2; ++i) {
        int p = i * 256 + t;            // block-local pooled px 0..511
        int pyl = p >> 5, px = p & 31;
        float v[4][4];
        #pragma unroll
        for (int r = 0; r < 4; ++r)
            #pragma unroll
            for (int c = 0; c < 4; ++c)
                v[r][c] = img[(2 * pyl + r) * 66 + (2 * px + c)];
        const int pg = (yb * 16 + pyl) * 32 + px;   // global pooled px
        unsigned short* dst = ob + (size_t)pg * 32;
        #pragma unroll 2
        for (int c4 = 0; c4 < 8; ++c4) {
            float o4[4];
            #pragma unroll
            for (int h = 0; h < 4; ++h) {
                const int c = c4 * 4 + h;
                float w[9];
                #pragma unroll
                for (int k = 0; k < 9; ++k) w[k] = ws[c * 9 + k];
                float s00 = 0.f, s01 = 0.f, s10 = 0.f, s11 = 0.f;
                #pragma unroll
                for (int ky = 0; ky < 3; ++ky)
                    #pragma unroll
                    for (int kx = 0; kx < 3; ++kx) {
                        float wk = w[ky * 3 + kx];
                        s00 = fmaf(v[ky][kx],         wk, s00);
                        s01 = fmaf(v[ky][kx + 1],     wk, s01);
                        s10 = fmaf(v[ky + 1][kx],     wk, s10);
                        s11 = fmaf(v[ky + 1][kx + 1], wk, s11);
                    }
                float bb = bs[c];
                o4[h] = 0.25f * (prelu(s00 + bb, alpha) + prelu(s01 + bb, alpha) +
                                 prelu(s10 + bb, alpha) + prelu(s11 + bb, alpha));
            }
            u32x2 q = {pack2(o4[0], o4[1]), pack2(o4[2], o4[3])};
            *reinterpret_cast<u32x2*>(dst + c4 * 4) = q;
        }
    }
}

// ---------------- Kernel 2: conv2 via bf16 MFMA. in1 NHWC [p][ci32], out2 NHWC [p][co64] ----
__global__ __launch_bounds__(512) void k_conv2_mfma(
    const unsigned short* __restrict__ in1, const unsigned short* __restrict__ wpk,
    const float* __restrict__ b2, const float* __restrict__ a2,
    unsigned short* __restrict__ out2)
{
    __shared__ __align__(16) unsigned short lb[4 * 18 * 36 * 8]; // 41.5 KB [cg][ly][sx][i8]
    __shared__ float bs[64];
    const int t = threadIdx.x;
    const int bl = blockIdx.x >> 1;
    const int yb = blockIdx.x & 1;
    const int lane = t & 63;
    const int w = t >> 6;
    const int mp = w >> 2;
    const int nq = w & 3;
    const int lg = lane >> 4;
    const int lo16 = lane & 15;

    if (t < 64) bs[t] = b2[t];

    const f32x4 zf = {0.f, 0.f, 0.f, 0.f};
    f32x4 acc[2][8];
    #pragma unroll
    for (int m = 0; m < 2; ++m)
        #pragma unroll
        for (int n = 0; n < 8; ++n) acc[m][n] = zf;

    const s16x8 zz = {0, 0, 0, 0, 0, 0, 0, 0};
    for (int idx = t; idx < 2592; idx += 512)
        reinterpret_cast<s16x8*>(lb)[idx] = zz;
    __syncthreads();

    for (int idx = t; idx < 576; idx += 512) {
        int ly = idx >> 5;
        int xx = idx & 31;
        int y = yb * 16 + ly - 1;
        if (y >= 0 && y < 32) {
            const s16x8* src = reinterpret_cast<const s16x8*>(
                in1 + ((size_t)bl * 1024 + y * 32 + xx) * 32);
            #pragma unroll
            for (int cg = 0; cg < 4; ++cg) {
                *reinterpret_cast<s16x8*>(&lb[((cg * 18 + ly) * 36 + (xx + 1)) * 8]) = src[cg];
            }
        }
    }
    __syncthreads();

    #pragma unroll
    for (int tap = 0; tap < 9; ++tap) {
        const int dy = tap / 3, dx = tap - dy * 3;
        const size_t wbase = ((size_t)tap * 4 + lg) * 512 + (size_t)(mp * 32 + lo16) * 8;
        s16x8 a0 = *reinterpret_cast<const s16x8*>(wpk + wbase);
        s16x8 a1 = *reinterpret_cast<const s16x8*>(wpk + wbase + 128);
        #pragma unroll
        for (int n = 0; n < 8; ++n) {
            const int rl = n >> 1, xh = n & 1;
            const int ly = nq * 4 + rl + dy;
            const int sx = xh * 16 + lo16 + dx;
            s16x8 bfrag = *reinterpret_cast<const s16x8*>(
                &lb[((lg * 18 + ly) * 36 + sx) * 8]);
            acc[0][n] = __builtin_amdgcn_mfma_f32_16x16x32_bf16(a0, bfrag, acc[0][n], 0, 0, 0);
            acc[1][n] = __builtin_amdgcn_mfma_f32_16x16x32_bf16(a1, bfrag, acc[1][n], 0, 0, 0);
        }
    }

    const float alpha = a2[0];
    #pragma unroll
    for (int m = 0; m < 2; ++m) {
        const int co = mp * 32 + m * 16 + lg * 4;
        #pragma unroll
        for (int pr = 0; pr < 2; ++pr) {
            #pragma unroll
            for (int xh = 0; xh < 2; ++xh) {
                float sr[4];
                #pragma unroll
                for (int r = 0; r < 4; ++r) {
                    const float bb = bs[co + r];
                    float v0 = acc[m][(pr * 2) * 2 + xh][r] + bb;
                    float v1 = acc[m][(pr * 2 + 1) * 2 + xh][r] + bb;
                    float s = prelu(v0, alpha) + prelu(v1, alpha);
                    s += __shfl_xor(s, 1, 64);
                    sr[r] = s * 0.25f;
                }
                if (!(lo16 & 1)) {
                    int gy = yb * 8 + nq * 2 + pr;
                    int gx = xh * 8 + (lo16 >> 1);
                    u32x2 q = {pack2(sr[0], sr[1]), pack2(sr[2], sr[3])};
                    *reinterpret_cast<u32x2*>(
                        out2 + ((size_t)bl * 256 + gy * 16 + gx) * 64 + co) = q;
                }
            }
        }
    }
}

// ---------------- Kernel 3: conv3 via bf16 MFMA. in2 NHWC [p256][ci64], full image/block ----
// out3h bf16 [b][2048] (k = co*16 + fy*4 + fx).
__global__ __launch_bounds__(512) void k_conv3_mfma(
    const unsigned short* __restrict__ in2, const unsigned short* __restrict__ wpk,
    const float* __restrict__ b3, const float* __restrict__ a3,
    unsigned short* __restrict__ out3h, int b0)
{
    __shared__ __align__(16) unsigned short lb[8 * 20 * 20 * 8]; // 51.2 KB
    __shared__ float bs[128];

    const int t = threadIdx.x;
    const int bl = blockIdx.x;
    const int lane = t & 63;
    const int w = t >> 6;
    const int mp = w >> 1;
    const int nh = w & 1;
    const int lg = lane >> 4;
    const int lo16 = lane & 15;

    if (t < 128) bs[t] = b3[t];

    const s16x8 zz = {0, 0, 0, 0, 0, 0, 0, 0};
    for (int idx = t; idx < 3200; idx += 512)
        reinterpret_cast<s16x8*>(lb)[idx] = zz;
    __syncthreads();

    for (int idx = t; idx < 2048; idx += 512) {
        int g = idx >> 8;
        int pix = idx & 255;
        int row = pix >> 4;
        int xx = pix & 15;
        s16x8 v = *reinterpret_cast<const s16x8*>(
            in2 + ((size_t)bl * 256 + row * 16 + xx) * 64 + g * 8);
        *reinterpret_cast<s16x8*>(&lb[((g * 20 + (row + 2)) * 20 + (xx + 2)) * 8]) = v;
    }
    __syncthreads();

    const f32x4 zf = {0.f, 0.f, 0.f, 0.f};
    f32x4 acc[2][8];
    #pragma unroll
    for (int m = 0; m < 2; ++m)
        #pragma unroll
        for (int n = 0; n < 8; ++n) acc[m][n] = zf;

    for (int kk = 0; kk < 2; ++kk) {
        for (int tap = 0; tap < 25; ++tap) {
            int dy = tap / 5, dx = tap - dy * 5;
            const size_t wbase = ((size_t)(tap * 2 + kk) * 4 + lg) * 1024
                               + (size_t)(mp * 32 + lo16) * 8;
            s16x8 a0 = *reinterpret_cast<const s16x8*>(wpk + wbase);
            s16x8 a1 = *reinterpret_cast<const s16x8*>(wpk + wbase + 128);
            #pragma unroll
            for (int n = 0; n < 8; ++n) {
                int ly = nh * 8 + n + dy;
                int ax = lo16 + dx;
                s16x8 bfrag = *reinterpret_cast<const s16x8*>(
                    &lb[(((kk * 4 + lg) * 20 + ly) * 20 + ax) * 8]);
                acc[0][n] = __builtin_amdgcn_mfma_f32_16x16x32_bf16(a0, bfrag, acc[0][n], 0, 0, 0);
                acc[1][n] = __builtin_amdgcn_mfma_f32_16x16x32_bf16(a1, bfrag, acc[1][n], 0, 0, 0);
            }
        }
    }

    const float alpha = a3[0];
    const int b = b0 + bl;
    const int fx = lo16 >> 2;
    #pragma unroll
    for (int m = 0; m < 2; ++m) {
        const int cobase = mp * 32 + m * 16 + lg * 4;
        #pragma unroll
        for (int r = 0; r < 4; ++r) {
            float bb = bs[cobase + r];
            #pragma unroll
            for (int half = 0; half < 2; ++half) {
                float s = 0.f;
                #pragma unroll
                for (int j = 0; j < 4; ++j) {
                    float v = acc[m][half * 4 + j][r] + bb;
                    s += v > 0.f ? v : alpha * v;
                }
                s += __shfl_xor(s, 1, 64);
                s += __shfl_xor(s, 2, 64);
                if ((lane & 3) == 0) {
                    int fy = nh * 2 + half;
                    out3h[(size_t)b * 2048 + (cobase + r) * 16 + fy * 4 + fx] =
                        bf16_rn(s * 0.0625f);
                }
            }
        }
    }
}

// ---------------- Kernel 4: fused fc1 (K=2048) + prelu + fc2 (K=256) via MFMA ----------------
// grid 32 blocks (32 batch rows each), 512 threads = 8 waves = 4 m-quarters x 2 n-tiles.
__global__ __launch_bounds__(512) void k_fc_mfma(
    const unsigned short* __restrict__ h, const unsigned short* __restrict__ w1pk,
    const float* __restrict__ bc1, const float* __restrict__ ac,
    const unsigned short* __restrict__ w2pk, const float* __restrict__ bc2,
    float* __restrict__ out)
{
    __shared__ __align__(16) unsigned short hid_lds[32][264];  // 16.5 KB, 16B-aligned rows
    __shared__ float bs1[256];
    __shared__ float bs2[128];
    const int t = threadIdx.x;
    const int lane = t & 63;
    const int w = t >> 6;
    const int nl = w & 1;          // n-tile (16 batch cols)
    const int mq = w >> 1;         // m-quarter (4 m-tiles for fc1, 2 for fc2)
    const int lg = lane >> 4;
    const int lo16 = lane & 15;

    if (t < 256) bs1[t] = bc1[t];
    if (t < 128) bs2[t] = bc2[t];

    const int b_local = nl * 16 + lo16;
    const size_t rb = (size_t)blockIdx.x * 32 + b_local;

    const f32x4 zf = {0.f, 0.f, 0.f, 0.f};
    f32x4 acc1[4];
    #pragma unroll
    for (int mt = 0; mt < 4; ++mt) acc1[mt] = zf;

    const unsigned short* hrow = h + rb * 2048;
    #pragma unroll 2
    for (int kc = 0; kc < 64; ++kc) {
        s16x8 bfrag = *reinterpret_cast<const s16x8*>(hrow + kc * 32 + lg * 8);
        #pragma unroll
        for (int mt = 0; mt < 4; ++mt) {
            s16x8 afr = *reinterpret_cast<const s16x8*>(
                w1pk + ((size_t)(kc * 4 + lg) * 256 + (mq * 4 + mt) * 16 + lo16) * 8);
            acc1[mt] = __builtin_amdgcn_mfma_f32_16x16x32_bf16(afr, bfrag, acc1[mt], 0, 0, 0);
        }
    }

    __syncthreads();   // bs1/bs2 visible
    const float alpha = ac[0];
    #pragma unroll
    for (int mt = 0; mt < 4; ++mt) {
        const int hid0 = (mq * 4 + mt) * 16 + lg * 4;
        float v0 = prelu(acc1[mt][0] + bs1[hid0 + 0], alpha);
        float v1 = prelu(acc1[mt][1] + bs1[hid0 + 1], alpha);
        float v2 = prelu(acc1[mt][2] + bs1[hid0 + 2], alpha);
        float v3 = prelu(acc1[mt][3] + bs1[hid0 + 3], alpha);
        u32x2 q = {pack2(v0, v1), pack2(v2, v3)};
        *reinterpret_cast<u32x2*>(&hid_lds[b_local][hid0]) = q;
    }
    __syncthreads();

    f32x4 acc2[2];
    acc2[0] = zf; acc2[1] = zf;
    #pragma unroll
    for (int kc = 0; kc < 8; ++kc) {
        s16x8 bfrag = *reinterpret_cast<const s16x8*>(&hid_lds[b_local][kc * 32 + lg * 8]);
        #pragma unroll
        for (int mt = 0; mt < 2; ++mt) {
            s16x8 afr = *reinterpret_cast<const s16x8*>(
                w2pk + ((size_t)(kc * 4 + lg) * 128 + (mq * 2 + mt) * 16 + lo16) * 8);
            acc2[mt] = __builtin_amdgcn_mfma_f32_16x16x32_bf16(afr, bfrag, acc2[mt], 0, 0, 0);
        }
    }

    #pragma unroll
    for (int mt = 0; mt < 2; ++mt) {
        const int o0 = (mq * 2 + mt) * 16 + lg * 4;
        #pragma unroll
        for (int r = 0; r < 4; ++r)
            out[rb * 128 + o0 + r] = acc2[mt][r] + bs2[o0 + r];
    }
}

extern "C" void kernel_launch(void* const* d_in, const int* in_sizes, int n_in,
                              void* d_out, int out_size, void* d_ws, size_t ws_size,
                              hipStream_t stream) {
    const float* x   = (const float*)d_in[0];
    const float* w1  = (const float*)d_in[1];
    const float* b1  = (const float*)d_in[2];
    const float* a1  = (const float*)d_in[3];
    const float* w2  = (const float*)d_in[4];
    const float* b2  = (const float*)d_in[5];
    const float* a2  = (const float*)d_in[6];
    const float* w3  = (const float*)d_in[7];
    const float* b3  = (const float*)d_in[8];
    const float* a3  = (const float*)d_in[9];
    const float* wc1 = (const float*)d_in[10];
    const float* bc1 = (const float*)d_in[11];
    const float* ac  = (const float*)d_in[12];
    const float* wc2 = (const float*)d_in[13];
    const float* bc2 = (const float*)d_in[14];
    float* out = (float*)d_out;

    const size_t OUT3_BYTES = (size_t)1024 * 2048 * 2;      // 4 MB (bf16)
    const size_t W3PK = (size_t)204800 * 2;                 // 400 KB
    const size_t W2PK = (size_t)18432 * 2;                  // 36 KB
    const size_t WFC1 = (size_t)524288 * 2;                 // 1 MB
    const size_t WFC2 = (size_t)32768 * 2;                  // 64 KB
    const size_t FIXED = OUT3_BYTES + W3PK + W2PK + WFC1 + WFC2;
    int C = 1024;
    while (C > 1 && FIXED + (size_t)C * (65536 + 32768) > ws_size) C >>= 1;

    char* p = (char*)d_ws;
    unsigned short* out3h = (unsigned short*)p;  p += OUT3_BYTES;
    unsigned short* w3pk  = (unsigned short*)p;  p += W3PK;
    unsigned short* w2pk  = (unsigned short*)p;  p += W2PK;
    unsigned short* wf1pk = (unsigned short*)p;  p += WFC1;
    unsigned short* wf2pk = (unsigned short*)p;  p += WFC2;
    unsigned short* out1  = (unsigned short*)p;  p += (size_t)C * 65536;
    unsigned short* out2  = (unsigned short*)p;

    k_prepack3<<<800, 256, 0, stream>>>(w3, w3pk);
    k_prepack2<<<72, 256, 0, stream>>>(w2, w2pk);
    k_prepack_fc1<<<2048, 256, 0, stream>>>(wc1, wf1pk);
    k_prepack_fc2<<<128, 256, 0, stream>>>(wc2, wf2pk);

    const int nchunk = 1024 / C;
    for (int c = 0; c < nchunk; ++c) {
        int b0 = c * C;
        k_scat_conv1<<<2 * C, 256, 0, stream>>>(x, w1, b1, a1, out1, b0);
        k_conv2_mfma<<<2 * C, 512, 0, stream>>>(out1, w2pk, b2, a2, out2);
        k_conv3_mfma<<<C, 512, 0, stream>>>(out2, w3pk, b3, a3, out3h, b0);
    }
    k_fc_mfma<<<32, 512, 0, stream>>>(out3h, wf1pk, bc1, ac, wf2pk, bc2, out);
}